// Round 6
// baseline (420.194 us; speedup 1.0000x reference)
//
#include <hip/hip_runtime.h>
#include <math.h>

typedef unsigned short u16;
typedef __attribute__((ext_vector_type(8))) __bf16 bf16x8;
typedef __attribute__((ext_vector_type(4))) float f32x4;
typedef __attribute__((ext_vector_type(4))) u16 u16x4;
typedef __attribute__((ext_vector_type(8))) u16 u16x8;
typedef __attribute__((ext_vector_type(4))) float float4v;

constexpr int kS = 1024;
constexpr int kD = 1024;
constexpr int kDinner = 2048;
constexpr int kHeads = 32;
constexpr int kConvDim = 2176;
constexpr int kDproj = 4256;
constexpr int kDprojPad = 4352;
constexpr int kRows = 2048;   // B*S
constexpr int kHmlp = 8192;
constexpr int kHhalf = 4096;
constexpr int kL = 64;        // scan chunk length
constexpr int kNC = 16;       // chunks per sequence

__device__ __forceinline__ float bf2f(u16 u) {
    return __builtin_bit_cast(float, (unsigned int)u << 16);
}
__device__ __forceinline__ u16 f2bf(float f) {
    unsigned int u = __builtin_bit_cast(unsigned int, f);
    u += 0x7fffu + ((u >> 16) & 1u);
    return (u16)(u >> 16);
}
__device__ __forceinline__ float silu_(float x) { return x / (1.f + __expf(-x)); }

// async global->LDS, 16B per lane; LDS dest = wave-uniform base + lane*16
__device__ __forceinline__ void gld16(const u16* g, u16* l) {
    __builtin_amdgcn_global_load_lds(
        (const __attribute__((address_space(1))) void*)g,
        (__attribute__((address_space(3))) void*)l, 16, 0, 0);
}

// ---------------- fused casts: all 5 fp32->bf16 conversions in one launch ----
// fc1 is row-PERMUTED on cast so the MLP gate pair (a_p, g_p) lands in columns
// c and c+16 of the SAME lane's accumulator blocks:
//   a-row p      -> col (p>>4)*32 + (p&15)
//   g-row 4096+p -> col (p>>4)*32 + (p&15) + 16
constexpr int kB1 = kRows * kD / 4;                       // x
constexpr int kB2 = kB1 + kDprojPad * kD / 4;             // in_proj (padded)
constexpr int kB3 = kB2 + kD * kDinner / 4;               // out_proj
constexpr int kB4 = kB3 + kHmlp * kD / 4;                 // fc1 (permuted)
constexpr int kB5 = kB4 + kD * kHhalf / 4;                // fc2
__global__ __launch_bounds__(256)
void cast_all_kernel(const float* __restrict__ x, const float* __restrict__ w1,
                     const float* __restrict__ w2, const float* __restrict__ w3,
                     const float* __restrict__ w4, u16* __restrict__ xbf,
                     u16* __restrict__ w1bf, u16* __restrict__ w2bf,
                     u16* __restrict__ w3bf, u16* __restrict__ w4bf) {
    int i = blockIdx.x * 256 + threadIdx.x;
    const float* src;
    u16* dst;
    int j;
    if (i < kB1) {
        j = i; src = x; dst = xbf;
    } else if (i < kB2) {
        j = i - kB1;
        int e = j * 4, row = e >> 10, col = e & 1023;
        u16x4 o = {0, 0, 0, 0};
        if (row < kDproj) {
            float4v v = *(const float4v*)(w1 + (size_t)row * kD + col);
            o.x = f2bf(v.x); o.y = f2bf(v.y); o.z = f2bf(v.z); o.w = f2bf(v.w);
        }
        ((u16x4*)w1bf)[j] = o;
        return;
    } else if (i < kB3) {
        j = i - kB2; src = w2; dst = w2bf;
    } else if (i < kB4) {
        j = i - kB3;
        int e = j * 4, row = e >> 10, col4 = (e & 1023) >> 2;
        int p = (row < kHhalf) ? row : row - kHhalf;
        int permrow = (p >> 4) * 32 + (p & 15) + ((row < kHhalf) ? 0 : 16);
        float4v v = ((const float4v*)w3)[j];
        u16x4 o;
        o.x = f2bf(v.x); o.y = f2bf(v.y); o.z = f2bf(v.z); o.w = f2bf(v.w);
        ((u16x4*)w3bf)[permrow * 256 + col4] = o;
        return;
    } else {
        j = i - kB4; src = w4; dst = w4bf;
    }
    float4v v = ((const float4v*)src)[j];
    u16x4 o;
    o.x = f2bf(v.x); o.y = f2bf(v.y); o.z = f2bf(v.z); o.w = f2bf(v.w);
    ((u16x4*)dst)[j] = o;
}

// ---------------- GEMM: C[M,N] = A[M,K] * W[N,K]^T ----------------
// m97 staging + double-buffered LDS, one barrier per K-iter. Used for the
// small-N GEMMs (G1/G2/G4) where 256^2 tiles would under-occupy the grid.
// blockIdx.z = split-K slice (partials at Cout + z*M*N, fp32, no resid).
template <bool OUT_BF16, bool GATED = false>
__global__ __launch_bounds__(256)
void gemm_bt(const u16* __restrict__ A, const u16* __restrict__ W,
             void* __restrict__ Cout, const float* __restrict__ resid,
             int M, int N, int K) {
    __shared__ u16 As[2][128 * 32];
    __shared__ u16 Bs[2][128 * 32];
    const int tid = threadIdx.x;
    const int lane = tid & 63;
    const int w = __builtin_amdgcn_readfirstlane(tid >> 6);
    const int wm = w >> 1, wn = w & 1;
    const int bm = blockIdx.y * 128;
    const int bn = blockIdx.x * 128;
    const int z = blockIdx.z;
    const int Kchunk = K / gridDim.z;
    const int k0 = z * Kchunk;

    f32x4 acc[4][4];
#pragma unroll
    for (int i = 0; i < 4; i++)
#pragma unroll
        for (int j = 0; j < 4; j++) acc[i][j] = {0.f, 0.f, 0.f, 0.f};

    // staging: lane -> (row = lane>>2, kchunk = lane&3): global-coalesced
    const int srow = lane >> 2;          // 0..15
    const int scol = (lane & 3) * 8;     // k elem
    const u16* gA = A + (size_t)(bm + w * 32 + srow) * K + k0 + scol;
    const u16* gB = W + (size_t)(bn + w * 32 + srow) * K + k0 + scol;
    const size_t rstep = (size_t)16 * K;

    const int sbase0 = (w * 32) * 32;
    const int sbase1 = (w * 32 + 16) * 32;
    const int fra = (lane & 15) * 32 + (lane >> 4) * 8;

    // prologue: stage tile 0 into buffer 0
    gld16(gA, &As[0][sbase0]);
    gld16(gA + rstep, &As[0][sbase1]);
    gld16(gB, &Bs[0][sbase0]);
    gld16(gB + rstep, &Bs[0][sbase1]);

    const int nk = Kchunk >> 5;
    for (int i = 0; i < nk; i++) {
        const int cur = i & 1, nxt = cur ^ 1;
        __syncthreads();   // drains DMA for buf[cur]; buf[nxt] reads finished
        if (i + 1 < nk) {
            int kt2 = (i + 1) * 32;
            gld16(gA + kt2, &As[nxt][sbase0]);
            gld16(gA + kt2 + rstep, &As[nxt][sbase1]);
            gld16(gB + kt2, &Bs[nxt][sbase0]);
            gld16(gB + kt2 + rstep, &Bs[nxt][sbase1]);
        }
        bf16x8 av[4], bv[4];
#pragma unroll
        for (int mi = 0; mi < 4; mi++)
            av[mi] = *(const bf16x8*)&As[cur][(wm * 64 + mi * 16) * 32 + fra];
#pragma unroll
        for (int ni = 0; ni < 4; ni++)
            bv[ni] = *(const bf16x8*)&Bs[cur][(wn * 64 + ni * 16) * 32 + fra];
#pragma unroll
        for (int mi = 0; mi < 4; mi++)
#pragma unroll
            for (int ni = 0; ni < 4; ni++)
                acc[mi][ni] = __builtin_amdgcn_mfma_f32_16x16x32_bf16(av[mi], bv[ni], acc[mi][ni], 0, 0, 0);
    }

    const int rb = bm + wm * 64 + ((lane >> 4) << 2);
    const int cb = bn + wn * 64 + (lane & 15);
    if (GATED) {
        u16* Cb = (u16*)Cout;
        const int NG = N >> 1;
        const int gc0 = ((bn + wn * 64) >> 1) + (lane & 15);
#pragma unroll
        for (int mi = 0; mi < 4; mi++) {
#pragma unroll
            for (int p = 0; p < 2; p++) {
#pragma unroll
                for (int r = 0; r < 4; r++) {
                    float a = acc[mi][2 * p][r];
                    float g = acc[mi][2 * p + 1][r];
                    Cb[(size_t)(rb + mi * 16 + r) * NG + gc0 + p * 16] =
                        f2bf(a * silu_(g));
                }
            }
        }
        return;
    }
    float* Cf = (float*)Cout + (size_t)z * M * N;
    u16* Cb = (u16*)Cout;
#pragma unroll
    for (int mi = 0; mi < 4; mi++) {
#pragma unroll
        for (int ni = 0; ni < 4; ni++) {
#pragma unroll
            for (int r = 0; r < 4; r++) {
                size_t offo = (size_t)(rb + mi * 16 + r) * N + (cb + ni * 16);
                float v = acc[mi][ni][r];
                if (resid) v += resid[offo];
                if (OUT_BF16) Cb[offo] = f2bf(v);
                else Cf[offo] = v;
            }
        }
    }
}

// ---------------- 256x256 8-phase GEMM (gated, for G3) — v5 ----------------
// v5: LDS-read-volume cut. R5 post-mortem arithmetic: with 8 waves (2Mx4N,
// 128x64 each), per-tile LDS reads = 8x(128+64)x64x2B = 192KB + 64KB DMA
// writes vs only ~2064cy of MFMA -> LDS is the critical path (predicted
// MfmaUtil ~25-30%; measured 30% across all schedule variants — schedule
// tweaks couldn't help an operand-volume problem). Re-partition to 4 waves
// x 128x128: per-tile reads = 4x(128+128)x64x2B = 128KB (-33%), making
// MFMA dominant. acc = 8x8 f32x4 = 256 VGPR (~334 total, <450 no-spill),
// 256 threads, 1 wave/SIMD. Staging: 4 gld16/unit (256 thr x 16B = 4KB);
// 16 loads/tile -> steady-state counted vmcnt(12) (wait = all of tile T+1).
#define VMCNT12 asm volatile("s_waitcnt vmcnt(12)" ::: "memory")
#define VMCNT0  asm volatile("s_waitcnt vmcnt(0)" ::: "memory")

__global__ __launch_bounds__(256, 1)
void gemm256_gated(const u16* __restrict__ A, const u16* __restrict__ W,
                   u16* __restrict__ Cout, int M, int N, int K) {
    __shared__ u16 lds[2][2][2][2][4096];   // [dbuf][mat][half][kh][128*32]
    const int tid = threadIdx.x;
    const int lane = tid & 63;
    const int w = __builtin_amdgcn_readfirstlane(tid >> 6);   // 0..3
    const int wm = w >> 1;                  // 0..1  (M half, 128 rows)
    const int wn = w & 1;                   // 0..1  (N half, 128 cols)

    // XCD-aware rectangle map (grid 8 M-tiles x 32 N-tiles = 256 blocks):
    const int lin = blockIdx.x;
    const int xcd = lin & 7, j = lin >> 3;
    const int bm = (((xcd >> 2) << 2) + (j & 3)) << 8;
    const int bn = (((xcd & 3) << 3) + (j >> 2)) << 8;

    // staging source (pre-swizzled k-slot; same involution as read side)
    const int rst = tid >> 2, sst = tid & 3;          // rows 0..63, 4 slots
    const int vst = (((rst >> 1) & 1) << 1) | ((rst >> 2) & 1);
    const u16* gA0 = A + (size_t)(bm + rst) * K + ((sst ^ vst) << 3);
    const u16* gB0 = W + (size_t)(bn + rst) * K + ((sst ^ vst) << 3);
    const size_t h64 = (size_t)64 * K;               // 64-row step (elems)
    const int wq512 = w * 512;                        // wave's 1KB DMA block

    // fragment read offset (swizzled): row-bits 1,2 XOR into the 16B slot
    const int r0a = lane & 15, slot = lane >> 4;
    const int v2a = (((r0a >> 1) & 1) << 1) | ((r0a >> 2) & 1);
    const int fro = r0a * 32 + ((slot ^ v2a) << 3);

    f32x4 acc[8][8];
#pragma unroll
    for (int i = 0; i < 8; i++)
#pragma unroll
        for (int j_ = 0; j_ < 8; j_++) acc[i][j_] = {0.f, 0.f, 0.f, 0.f};
    bf16x8 bv[8];
    const int nt = K >> 6;                  // K-tiles of 64

// 4 gld16 per unit: (mat, kh) covers both 128-row halves, 64 rows per call
#define STAGE(d, mat, kh, kt)                                               \
    { const u16* g_ = ((mat) ? gB0 : gA0) + (size_t)(kt) * 64 + (kh) * 32;  \
      gld16(g_,            &lds[d][mat][0][kh][wq512]);                     \
      gld16(g_ + h64,      &lds[d][mat][0][kh][2048 + wq512]);              \
      gld16(g_ + 2 * h64,  &lds[d][mat][1][kh][wq512]);                     \
      gld16(g_ + 3 * h64,  &lds[d][mat][1][kh][2048 + wq512]); }

#define LDA_FRAG(dst, d, kh, mfb)                                           \
    _Pragma("unroll") for (int i_ = 0; i_ < 4; i_++)                        \
        dst[i_] = *(const bf16x8*)&lds[d][0][wm][kh][((mfb) + i_) * 512 + fro];

#define LDB_FRAG(d, kh)                                                     \
    _Pragma("unroll") for (int i_ = 0; i_ < 8; i_++)                        \
        bv[i_] = *(const bf16x8*)&lds[d][1][wn][kh][i_ * 512 + fro];

#define PHASE_TAIL(mfb, ...)                                                \
    __builtin_amdgcn_s_barrier();                                           \
    asm volatile("s_waitcnt lgkmcnt(0)" ::: "memory");                      \
    __builtin_amdgcn_s_setprio(1);                                          \
    _Pragma("unroll") for (int i_ = 0; i_ < 4; i_++)                        \
        _Pragma("unroll") for (int n_ = 0; n_ < 8; n_++)                    \
            acc[(mfb) + i_][n_] = __builtin_amdgcn_mfma_f32_16x16x32_bf16(  \
                av[i_], bv[n_], acc[(mfb) + i_][n_], 0, 0, 0);              \
    __builtin_amdgcn_s_setprio(0);                                          \
    __VA_ARGS__;                                                            \
    __builtin_amdgcn_s_barrier();

// Region-overwrite discipline: reads A-kh0 in ph0/ph1, B-kh0 in ph0/ph1
// (bv persists), A-kh1 ph2/ph3, B-kh1 ph2/ph3; each STAGE lands >= 1 phase
// after its region's last read (reads drain at that phase's lgkmcnt(0),
// published by the closing barrier).
#define TILE(T, D)                                                          \
    { /* ph0: kh0, mf0-3 */                                                 \
      { bf16x8 av[4]; LDB_FRAG(D, 0); LDA_FRAG(av, D, 0, 0);                \
        if ((T) + 1 < nt) STAGE(D ^ 1, 0, 1, (T) + 1);                      \
        PHASE_TAIL(0, ((void)0)) }                                          \
      /* ph1: kh0, mf4-7 */                                                 \
      { bf16x8 av[4]; LDA_FRAG(av, D, 0, 4);                                \
        if ((T) + 2 < nt) STAGE(D, 1, 0, (T) + 2);                          \
        PHASE_TAIL(4, ((void)0)) }                                          \
      /* ph2: kh1, mf0-3 */                                                 \
      { bf16x8 av[4]; LDB_FRAG(D, 1); LDA_FRAG(av, D, 1, 0);                \
        if ((T) + 2 < nt) STAGE(D, 0, 0, (T) + 2);                          \
        PHASE_TAIL(0, ((void)0)) }                                          \
      /* ph3: kh1, mf4-7 + the tile's single counted vmcnt */               \
      { bf16x8 av[4]; LDA_FRAG(av, D, 1, 4);                                \
        if ((T) + 2 < nt) STAGE(D, 1, 1, (T) + 2);                          \
        PHASE_TAIL(4, if ((T) + 2 < nt) { VMCNT12; }                        \
                      else if ((T) + 1 < nt) { VMCNT0; }) }                 \
    }

    // prologue: tile0 all 4 units + tile1 first 3 (A-k1(t1) staged by
    // TILE(0).ph0). 28 loads out; vmcnt(12) = tile0's 16 landed.
    STAGE(0, 1, 0, 0);   // B-k0 (t0)
    STAGE(0, 0, 0, 0);   // A-k0 (t0)
    STAGE(0, 1, 1, 0);   // B-k1 (t0)
    STAGE(0, 0, 1, 0);   // A-k1 (t0)
    STAGE(1, 1, 0, 1);   // B-k0 (t1)
    STAGE(1, 0, 0, 1);   // A-k0 (t1)
    STAGE(1, 1, 1, 1);   // B-k1 (t1)
    VMCNT12;
    __builtin_amdgcn_s_barrier();

    for (int tt = 0; tt < nt; tt += 2) {
        TILE(tt, 0)
        TILE(tt + 1, 1)
    }

#undef TILE
#undef PHASE_TAIL
#undef LDB_FRAG
#undef LDA_FRAG
#undef STAGE

    // gated epilogue: a*silu(g) -> LDS (padded rows) -> coalesced stores.
    // nf pair (2p, 2p+1) of the same lane, p 0..3; local gate-col =
    // wn*64 + p*16 + r0a; local row = wm*128 + mf*16 + slot*4 + r.
    __syncthreads();                       // staging LDS dead; safe to reuse
    u16* cst = (u16*)&lds[0][0][0][0][0];
    constexpr int LDE = 136;               // 272B rows: 16B-aligned, bank-spread
#pragma unroll
    for (int mf = 0; mf < 8; mf++) {
#pragma unroll
        for (int p = 0; p < 4; p++) {
#pragma unroll
            for (int r = 0; r < 4; r++) {
                float a = acc[mf][2 * p][r];
                float g = acc[mf][2 * p + 1][r];
                cst[(wm * 128 + mf * 16 + slot * 4 + r) * LDE +
                    wn * 64 + p * 16 + r0a] = f2bf(a * silu_(g));
            }
        }
    }
    __syncthreads();
    const int NG = N >> 1;
#pragma unroll
    for (int k = 0; k < 16; k++) {
        int ch = k * 256 + tid;            // 4096 chunks of 8 u16 (16B)
        int row = ch >> 4, c8 = (ch & 15) * 8;
        *(u16x8*)(Cout + (size_t)(bm + row) * NG + (bn >> 1) + c8) =
            *(const u16x8*)&cst[row * LDE + c8];
    }
}

// ---------------- split-K reduce (SK=4) + residual, fp32 out ----------------
__global__ __launch_bounds__(256)
void splitk_reduce_kernel(const float* __restrict__ Cp, const float* __restrict__ resid,
                          float* __restrict__ out, int mn4) {
    int i = blockIdx.x * 256 + threadIdx.x;
    if (i >= mn4) return;
    constexpr size_t MN = (size_t)kRows * kD;
    float4v s0 = ((const float4v*)Cp)[i];
    float4v s1 = ((const float4v*)(Cp + MN))[i];
    float4v s2 = ((const float4v*)(Cp + 2 * MN))[i];
    float4v s3 = ((const float4v*)(Cp + 3 * MN))[i];
    float4v r = ((const float4v*)resid)[i];
    float4v o;
    o.x = s0.x + s1.x + s2.x + s3.x + r.x;
    o.y = s0.y + s1.y + s2.y + s3.y + r.y;
    o.z = s0.z + s1.z + s2.z + s3.z + r.z;
    o.w = s0.w + s1.w + s2.w + s3.w + r.w;
    ((float4v*)out)[i] = o;
}

// ------- fused: split-K reduce + residual + RMSNorm(1024) -> x2 fp32, xn bf16
__global__ __launch_bounds__(256)
void reduce_rms_kernel(const float* __restrict__ Cp, const float* __restrict__ resid,
                       float* __restrict__ x2, const float* __restrict__ rmsw,
                       u16* __restrict__ xnbf) {
    const int row = blockIdx.x;
    const int tid = threadIdx.x;
    constexpr size_t MN = (size_t)kRows * kD;
    size_t i = (size_t)row * (kD / 4) + tid;
    float4v s0 = ((const float4v*)Cp)[i];
    float4v s1 = ((const float4v*)(Cp + MN))[i];
    float4v s2 = ((const float4v*)(Cp + 2 * MN))[i];
    float4v s3 = ((const float4v*)(Cp + 3 * MN))[i];
    float4v r = ((const float4v*)resid)[i];
    float4v v;
    v.x = s0.x + s1.x + s2.x + s3.x + r.x;
    v.y = s0.y + s1.y + s2.y + s3.y + r.y;
    v.z = s0.z + s1.z + s2.z + s3.z + r.z;
    v.w = s0.w + s1.w + s2.w + s3.w + r.w;
    ((float4v*)x2)[i] = v;
    float ss = v.x * v.x + v.y * v.y + v.z * v.z + v.w * v.w;
#pragma unroll
    for (int off = 32; off > 0; off >>= 1) ss += __shfl_down(ss, off);
    __shared__ float red[4];
    int wv = tid >> 6, lane = tid & 63;
    if (lane == 0) red[wv] = ss;
    __syncthreads();
    ss = red[0] + red[1] + red[2] + red[3];
    float rstd = rsqrtf(ss * (1.f / kD) + 1e-5f);
    float4v wv4 = ((const float4v*)rmsw)[tid];
    u16x4 o;
    o.x = f2bf(v.x * rstd * wv4.x);
    o.y = f2bf(v.y * rstd * wv4.y);
    o.z = f2bf(v.z * rstd * wv4.z);
    o.w = f2bf(v.w * rstd * wv4.w);
    ((u16x4*)xnbf)[i] = o;
}

// ---------------- fused depthwise causal conv + silu + dt ----------------
__global__ __launch_bounds__(256)
void convdt_kernel(const u16* __restrict__ zxbf, const float* __restrict__ convw,
                   const float* __restrict__ convb, u16* __restrict__ xsbf,
                   float* __restrict__ BCf, const float* __restrict__ dt_bias,
                   float* __restrict__ dtf) {
    int c = blockIdx.x * 256 + threadIdx.x;
    int row = blockIdx.y;                 // b*1024 + s
    if (c >= kConvDim + kHeads) return;
    if (c < kConvDim) {
        int s = row & (kS - 1);
        float acc = convb[c];
#pragma unroll
        for (int j = 0; j < 4; j++) {
            int sj = s - 3 + j;
            if (sj >= 0)
                acc += bf2f(zxbf[(size_t)(row - 3 + j) * kDprojPad + kDinner + c]) * convw[c * 4 + j];
        }
        float v = silu_(acc);
        if (c < kDinner) xsbf[(size_t)row * kDinner + c] = f2bf(v);
        else BCf[(size_t)row * 128 + (c - kDinner)] = v;
    } else {
        int h = c - kConvDim;
        float raw = bf2f(zxbf[(size_t)row * kDprojPad + (kDinner + kConvDim) + h]) + dt_bias[h];
        float dt = (raw > 20.f) ? raw : log1pf(__expf(raw));
        dtf[(size_t)row * kHeads + h] = dt;
    }
}

// ---------------- Phase A: intra-chunk scan as chunked matmul (MFMA) --------
// Mamba-2 chunk form, per (b,h,chunk):
//   la[t]  = -A_h * cumsum(dt)        (log of cumulative decay a[t])
//   G      = C @ B^T                  (64x64, K=n=64)
//   M[t,s] = G[t,s]*dt_s*exp(la_t-la_s), masked s<=t
//   Y      = M @ X  (+ D*x)          (64x64, K=s=64)
//   S[p,n] = sum_s x[s,p]*dt_s*exp(la63-la_s)*B[s,n]   (chunk-end state)
// Precision: hi/lo compensated bf16 splits keep all products fp32-accurate.
__global__ __launch_bounds__(256)
void scan_chunk_kernel(const u16* __restrict__ xsbf, const float* __restrict__ BCf,
                       const float* __restrict__ dtf, const float* __restrict__ A_log,
                       const float* __restrict__ Dv, u16* __restrict__ ysbf,
                       float* __restrict__ Pf, float* __restrict__ Scf) {
    constexpr int LDT = 72;   // row stride (elems); 144B rows -> conflict-free b128
    __shared__ __align__(16) char smem[65280];
    u16* Chi  = (u16*)(smem);
    u16* Clo  = (u16*)(smem + 9216);
    u16* Bhi  = (u16*)(smem + 18432);
    u16* Blo  = (u16*)(smem + 27648);
    u16* BThi = (u16*)(smem + 36864);
    u16* BTlo = (u16*)(smem + 46080);
    u16* xT   = (u16*)(smem + 55296);
    float* laS  = (float*)(smem + 64512);
    float* dtS  = (float*)(smem + 64768);
    float* wscS = (float*)(smem + 65024);
    // overlays (all transitions barrier-separated):
    u16* Mhi  = Clo;   // Clo dead after G
    u16* Mlo  = Bhi;   // Bhi dead after G + transpose
    u16* ybuf = Chi;   // Chi dead after G

    const int c = blockIdx.x, h = blockIdx.y, b = blockIdx.z;
    const int tid = threadIdx.x;
    const int lane = tid & 63;
    const int w = __builtin_amdgcn_readfirstlane(tid >> 6);
    const int row0 = b * kS + c * kL;
    const int frow = lane & 15;
    const int fk = (lane >> 4) * 8;
    const int q4 = (lane >> 4) * 4;
    const int w16 = w * 16;

    // ---- stage B/C (hi/lo split) ----
#pragma unroll
    for (int k = 0; k < 8; k++) {
        int e4 = k * 256 + tid;              // 2048 float4s = 64 rows x 128
        int t = e4 >> 5, col = (e4 & 31) * 4;
        float4v v = *(const float4v*)(BCf + (size_t)(row0 + t) * 128 + col);
        u16x4 hi, lo;
        hi.x = f2bf(v.x); lo.x = f2bf(v.x - bf2f(hi.x));
        hi.y = f2bf(v.y); lo.y = f2bf(v.y - bf2f(hi.y));
        hi.z = f2bf(v.z); lo.z = f2bf(v.z - bf2f(hi.z));
        hi.w = f2bf(v.w); lo.w = f2bf(v.w - bf2f(hi.w));
        int cc = col & 63;
        u16* dh = (col < 64) ? Bhi : Chi;
        u16* dl = (col < 64) ? Blo : Clo;
        *(u16x4*)&dh[t * LDT + cc] = hi;
        *(u16x4*)&dl[t * LDT + cc] = lo;
    }
    // ---- stage x transposed: xT[p][t] ----
#pragma unroll
    for (int k = 0; k < 2; k++) {
        int e8 = k * 256 + tid;
        int t = e8 >> 3, p8 = (e8 & 7) * 8;
        u16x8 xv = *(const u16x8*)(xsbf + (size_t)(row0 + t) * kDinner + h * 64 + p8);
#pragma unroll
        for (int j = 0; j < 8; j++) xT[(p8 + j) * LDT + t] = xv[j];
    }
    // ---- dt load + log-decay prefix scan (wave 0) ----
    if (tid < 64) {
        float d = dtf[(size_t)(row0 + tid) * kHeads + h];
        dtS[tid] = d;
        float cs = d;
#pragma unroll
        for (int off = 1; off < 64; off <<= 1) {
            float o = __shfl_up(cs, off);
            if (lane >= off) cs += o;
        }
        float A_h = __expf(A_log[h]);
        float la = -A_h * cs;
        laS[tid] = la;
        Pf[(size_t)(row0 + tid) * kHeads + h] = __expf(la);
        float la63 = __shfl(la, 63);
        wscS[tid] = d * __expf(la63 - la);
    }
    __syncthreads();

    // ---- G = C @ B^T (only lower-triangular tile columns nt <= w) ----
    f32x4 accG[4];
#pragma unroll
    for (int i = 0; i < 4; i++) accG[i] = {0.f, 0.f, 0.f, 0.f};
#pragma unroll
    for (int kb = 0; kb < 2; kb++) {
        bf16x8 ch = *(const bf16x8*)&Chi[(w16 + frow) * LDT + kb * 32 + fk];
        bf16x8 cl = *(const bf16x8*)&Clo[(w16 + frow) * LDT + kb * 32 + fk];
#pragma unroll
        for (int nt = 0; nt < 4; nt++) {
            if (nt <= w) {
                bf16x8 bh = *(const bf16x8*)&Bhi[(nt * 16 + frow) * LDT + kb * 32 + fk];
                bf16x8 bl = *(const bf16x8*)&Blo[(nt * 16 + frow) * LDT + kb * 32 + fk];
                accG[nt] = __builtin_amdgcn_mfma_f32_16x16x32_bf16(ch, bh, accG[nt], 0, 0, 0);
                accG[nt] = __builtin_amdgcn_mfma_f32_16x16x32_bf16(ch, bl, accG[nt], 0, 0, 0);
                accG[nt] = __builtin_amdgcn_mfma_f32_16x16x32_bf16(cl, bh, accG[nt], 0, 0, 0);
            }
        }
    }
    // ---- BT transpose (for S's B-operand) ----
#pragma unroll
    for (int k = 0; k < 16; k++) {
        int e = k * 256 + tid;
        int s = e >> 6, n = e & 63;
        BThi[n * LDT + s] = Bhi[s * LDT + n];
        BTlo[n * LDT + s] = Blo[s * LDT + n];
    }
    __syncthreads();   // G reads of Clo/Bhi/Chi done -> M/ybuf overlays legal

    // ---- M build: scale G by dt_s * exp(la_t - la_s), mask, hi/lo split ----
    f32x4 la4 = *(const f32x4*)&laS[w16 + q4];
#pragma unroll
    for (int nt = 0; nt < 4; nt++) {
        int s = nt * 16 + frow;
        float las = laS[s], dts = dtS[s];
#pragma unroll
        for (int r = 0; r < 4; r++) {
            int t = w16 + q4 + r;
            float f = 0.f;
            if (nt <= w && s <= t)
                f = dts * __expf(la4[r] - las) * accG[nt][r];
            u16 mh = f2bf(f);
            u16 ml = f2bf(f - bf2f(mh));
            Mhi[t * LDT + s] = mh;
            Mlo[t * LDT + s] = ml;
        }
    }

    // ---- Y = M @ X  (per-wave own rows; same-wave LDS RAW is in-order) ----
    f32x4 accY[4];
#pragma unroll
    for (int i = 0; i < 4; i++) accY[i] = {0.f, 0.f, 0.f, 0.f};
#pragma unroll
    for (int kb = 0; kb < 2; kb++) {
        bf16x8 mh = *(const bf16x8*)&Mhi[(w16 + frow) * LDT + kb * 32 + fk];
        bf16x8 ml = *(const bf16x8*)&Mlo[(w16 + frow) * LDT + kb * 32 + fk];
#pragma unroll
        for (int nt = 0; nt < 4; nt++) {
            bf16x8 xv = *(const bf16x8*)&xT[(nt * 16 + frow) * LDT + kb * 32 + fk];
            accY[nt] = __builtin_amdgcn_mfma_f32_16x16x32_bf16(mh, xv, accY[nt], 0, 0, 0);
            accY[nt] = __builtin_amdgcn_mfma_f32_16x16x32_bf16(ml, xv, accY[nt], 0, 0, 0);
        }
    }

    // ---- S = Xw^T @ B  (Xw = x * dt * exp(la63-la), hi/lo in regs) ----
    f32x4 accS[4];
#pragma unroll
    for (int i = 0; i < 4; i++) accS[i] = {0.f, 0.f, 0.f, 0.f};
#pragma unroll
    for (int kb = 0; kb < 2; kb++) {
        u16x8 xu = __builtin_bit_cast(u16x8, *(const bf16x8*)&xT[(w16 + frow) * LDT + kb * 32 + fk]);
        f32x4 w0v = *(const f32x4*)&wscS[kb * 32 + fk];
        f32x4 w1v = *(const f32x4*)&wscS[kb * 32 + fk + 4];
        u16x8 xh, xl;
#pragma unroll
        for (int j = 0; j < 8; j++) {
            float wv = (j < 4) ? w0v[j] : w1v[j - 4];
            float f = bf2f(xu[j]) * wv;
            u16 hh = f2bf(f);
            xh[j] = hh;
            xl[j] = f2bf(f - bf2f(hh));
        }
        bf16x8 xwh = __builtin_bit_cast(bf16x8, xh);
        bf16x8 xwl = __builtin_bit_cast(bf16x8, xl);
#pragma unroll
        for (int nt = 0; nt < 4; nt++) {
            bf16x8 bh = *(const bf16x8*)&BThi[(nt * 16 + frow) * LDT + kb * 32 + fk];
            bf16x8 bl = *(const bf16x8*)&BTlo[(nt * 16 + frow) * LDT + kb * 32 + fk];
            accS[nt] = __builtin_amdgcn_mfma_f32_16x16x32_bf16(xwh, bh, accS[nt], 0, 0, 0);
            accS[nt] = __builtin_amdgcn_mfma_f32_16x16x32_bf16(xwh, bl, accS[nt], 0, 0, 0);
            accS[nt] = __builtin_amdgcn_mfma_f32_16x16x32_bf16(xwl, bh, accS[nt], 0, 0, 0);
        }
    }

    // ---- epilogue: Y += D*x -> ybuf; S -> Scf ----
    const float Dh = Dv[h];
    const int bhc = (b * 32 + h) * kNC + c;
    float* Sb = Scf + (size_t)bhc * 4096;
#pragma unroll
    for (int nt = 0; nt < 4; nt++) {
#pragma unroll
        for (int r = 0; r < 4; r++) {
            int t = w16 + q4 + r;
            int pc = nt * 16 + frow;
            float y = accY[nt][r] + Dh * bf2f(xT[pc * LDT + t]);
            ybuf[t * 64 + pc] = f2bf(y);
            Sb[t * 64 + pc] = accS[nt][r];   // t here = p-row (same index math)
        }
    }
    __syncthreads();
#pragma unroll
    for (int k = 0; k < 2; k++) {
        int e8 = k * 256 + tid;
        int t = e8 >> 3, col8 = (e8 & 7) * 8;
        *(u16x8*)(ysbf + (size_t)(row0 + t) * kDinner + h * 64 + col8) =
            *(u16x8*)&ybuf[t * 64 + col8];
    }
}

// ---------------- Phase B: sequential chunk-state combine ----------------
// v2: 64 -> 1024 blocks. The recurrence is serial only in c; the 4096 state
// columns per (b,h) are independent -> split into 16 slices of 256. Old form
// ran 64 blocks = 25% of CUs on ~31MB of traffic (occupancy-bound).
__global__ __launch_bounds__(256)
void chunk_state_kernel(const float* __restrict__ Scf, const float* __restrict__ Pf,
                        float* __restrict__ Hinf) {
    const int bh = blockIdx.x;            // 64 = (b,h)
    const int b = bh >> 5, h = bh & 31;
    const int eo = blockIdx.y * 256 + threadIdx.x;   // state elem 0..4095
    float hreg = 0.f;
    for (int c = 0; c < kNC - 1; c++) {
        float Q = Pf[(size_t)(b * kS + c * kL + kL - 1) * kHeads + h];
        hreg = Q * hreg + Scf[(size_t)(bh * kNC + c) * 4096 + eo];
        Hinf[(size_t)(bh * kNC + c + 1) * 4096 + eo] = hreg;
    }
}

// ---------------- Phase C: cross-chunk correction ----------------
__global__ __launch_bounds__(256)
void chunk_corr_kernel(const float* __restrict__ Hinf, const float* __restrict__ BCf,
                       const float* __restrict__ Pf, u16* __restrict__ ysbf) {
    const int c = blockIdx.x + 1;
    const int h = blockIdx.y, b = blockIdx.z;
    const int tid = threadIdx.x;
    const int lane = tid & 63, wq = tid >> 6;
    __shared__ float Hin_lds[64 * 65];
    __shared__ float C_lds[kL * 64];
    const int bh = b * 32 + h;
    const size_t hbase = (size_t)(bh * kNC + c) * 4096;
#pragma unroll
    for (int k = 0; k < 16; k++) {
        int e = k * 256 + tid;
        Hin_lds[(e >> 6) * 65 + (e & 63)] = Hinf[hbase + e];
    }
    const int row0 = b * kS + c * kL;
#pragma unroll
    for (int k = 0; k < 4; k++) {
        int e4 = k * 256 + tid;
        int t = e4 >> 4, n4 = (e4 & 15) * 4;
        *(float4v*)&C_lds[t * 64 + n4] =
            *(const float4v*)(BCf + (size_t)(row0 + t) * 128 + 64 + n4);
    }
    __syncthreads();

    float hr[64];
#pragma unroll
    for (int n = 0; n < 64; n++) hr[n] = Hin_lds[lane * 65 + n];

    for (int tt = 0; tt < 16; tt++) {
        int t = wq * 16 + tt;
        float corr = 0.f;
#pragma unroll
        for (int n4 = 0; n4 < 16; n4++) {
            float4v cv = *(const float4v*)&C_lds[t * 64 + n4 * 4];
            corr += cv.x * hr[n4 * 4] + cv.y * hr[n4 * 4 + 1] +
                    cv.z * hr[n4 * 4 + 2] + cv.w * hr[n4 * 4 + 3];
        }
        float Pt = Pf[(size_t)(row0 + t) * kHeads + h];
        size_t yoff = (size_t)(row0 + t) * kDinner + h * 64 + lane;
        ysbf[yoff] = f2bf(bf2f(ysbf[yoff]) + Pt * corr);
    }
}

// ---------------- gate (silu(z)) + rmsnorm over 2048 ----------------
__global__ __launch_bounds__(256)
void gatenorm_kernel(const u16* __restrict__ ysbf, const u16* __restrict__ zxbf,
                     const float* __restrict__ normw, u16* __restrict__ ybf) {
    const int row = blockIdx.x;
    const int tid = threadIdx.x;
    float v[8];
    float ss = 0.f;
#pragma unroll
    for (int i = 0; i < 8; i++) {
        int idx = i * 256 + tid;
        float y = bf2f(ysbf[(size_t)row * kDinner + idx]);
        float z = bf2f(zxbf[(size_t)row * kDprojPad + idx]);
        v[i] = y * silu_(z);
        ss += v[i] * v[i];
    }
#pragma unroll
    for (int off = 32; off > 0; off >>= 1) ss += __shfl_down(ss, off);
    __shared__ float red[4];
    int wv = tid >> 6, lane = tid & 63;
    if (lane == 0) red[wv] = ss;
    __syncthreads();
    ss = red[0] + red[1] + red[2] + red[3];
    float rstd = rsqrtf(ss * (1.f / kDinner) + 1e-5f);
#pragma unroll
    for (int i = 0; i < 8; i++) {
        int idx = i * 256 + tid;
        ybf[(size_t)row * kDinner + idx] = f2bf(v[i] * rstd * normw[idx]);
    }
}

extern "C" void kernel_launch(void* const* d_in, const int* in_sizes, int n_in,
                              void* d_out, int out_size, void* d_ws, size_t ws_size,
                              hipStream_t stream) {
    const float* x         = (const float*)d_in[0];
    const float* in_proj_w = (const float*)d_in[1];
    const float* conv_w    = (const float*)d_in[2];
    const float* conv_b    = (const float*)d_in[3];
    const float* dt_bias   = (const float*)d_in[4];
    const float* A_log     = (const float*)d_in[5];
    const float* Dvec      = (const float*)d_in[6];
    const float* ssm_norm_w= (const float*)d_in[7];
    const float* out_proj_w= (const float*)d_in[8];
    const float* rms_w     = (const float*)d_in[9];
    const float* fc1_w     = (const float*)d_in[10];
    const float* fc2_w     = (const float*)d_in[11];
    float* out = (float*)d_out;

    char* ws = (char*)d_ws;
    size_t off = 0;
    auto alloc = [&](size_t bytes) -> void* {
        void* p = ws + off;
        off += (bytes + 255) & ~(size_t)255;
        return p;
    };
    u16*   xbf  = (u16*)alloc((size_t)kRows * kD * 2);
    u16*   w1bf = (u16*)alloc((size_t)kDprojPad * kD * 2);
    u16*   w2bf = (u16*)alloc((size_t)kD * kDinner * 2);
    u16*   w3bf = (u16*)alloc((size_t)kHmlp * kD * 2);
    u16*   w4bf = (u16*)alloc((size_t)kD * kHhalf * 2);
    u16*   zxbf = (u16*)alloc((size_t)kRows * kDprojPad * 2);
    u16*   xsbf = (u16*)alloc((size_t)kRows * kDinner * 2);
    float* BCf  = (float*)alloc((size_t)kRows * 128 * 4);
    float* dtf  = (float*)alloc((size_t)kRows * kHeads * 4);
    float* Pf   = (float*)alloc((size_t)kRows * kHeads * 4);
    u16*   ysbf = (u16*)alloc((size_t)kRows * kDinner * 2);
    u16*   ybf  = (u16*)alloc((size_t)kRows * kDinner * 2);
    float* x2   = (float*)alloc((size_t)kRows * kD * 4);
    u16*   xnbf = (u16*)alloc((size_t)kRows * kD * 2);
    u16*   h1bf = (u16*)alloc((size_t)kRows * kHmlp * 2);   // scratch region
    u16*   gbf  = (u16*)alloc((size_t)kRows * kHhalf * 2);
    // Aliased scratch (h1bf region is scratch-only now):
    //   Scf/Hinf (16MB each) during scan; Cp (4*2048*1024 f32 = 33.55MB)
    //   during G2 split-K and G4 split-K.
    float* Scf  = (float*)gbf;
    float* Hinf = (float*)h1bf;
    float* Cp   = (float*)h1bf;
    (void)ws_size; (void)in_sizes; (void)n_in; (void)out_size;

    // all casts in one dispatch (fc1 row-permuted for the gated epilogue)
    cast_all_kernel<<<kB5 / 256, 256, 0, stream>>>(
        x, in_proj_w, out_proj_w, fc1_w, fc2_w, xbf, w1bf, w2bf, w3bf, w4bf);

    // G1: zxbcdt = x @ in_proj^T   (2048 x 4352, bf16 out)
    gemm_bt<true><<<dim3(kDprojPad / 128, kRows / 128, 1), 256, 0, stream>>>(
        xbf, w1bf, zxbf, nullptr, kRows, kDprojPad, kD);

    // fused conv + dt
    convdt_kernel<<<dim3((kConvDim + kHeads + 255) / 256, kRows), 256, 0, stream>>>(
        zxbf, conv_w, conv_b, xsbf, BCf, dt_bias, dtf);

    // chunked scan (Phase A MFMA chunked-matmul form)
    scan_chunk_kernel<<<dim3(kNC, kHeads, 2), 256, 0, stream>>>(
        xsbf, BCf, dtf, A_log, Dvec, ysbf, Pf, Scf);
    chunk_state_kernel<<<dim3(64, 16), 256, 0, stream>>>(Scf, Pf, Hinf);
    chunk_corr_kernel<<<dim3(kNC - 1, kHeads, 2), 256, 0, stream>>>(Hinf, BCf, Pf, ysbf);

    gatenorm_kernel<<<kRows, 256, 0, stream>>>(ysbf, zxbf, ssm_norm_w, ybf);

    // G2: x2 = y @ out_proj^T + x   (split-K=4 partials, then fused reduce+rms)
    gemm_bt<false><<<dim3(kD / 128, kRows / 128, 4), 256, 0, stream>>>(
        ybf, w2bf, Cp, nullptr, kRows, kD, kDinner);
    reduce_rms_kernel<<<kRows, 256, 0, stream>>>(Cp, x, x2, rms_w, xnbf);

    // G3+gate fused (256^2 4-wave v5): g = a*silu(g') from permuted fc1
    gemm256_gated<<<dim3((kRows >> 8) * (kHmlp >> 8)), 256, 0, stream>>>(
        xnbf, w3bf, gbf, kRows, kHmlp, kD);

    // G4: out = g @ fc2^T + x2   (split-K=4 partials, then reduce+resid)
    gemm_bt<false><<<dim3(kD / 128, kRows / 128, 4), 256, 0, stream>>>(
        gbf, w4bf, Cp, nullptr, kRows, kD, kHhalf);
    splitk_reduce_kernel<<<(kRows * kD / 4 + 255) / 256, 256, 0, stream>>>(
        Cp, x2, out, kRows * kD / 4);
}

// Round 7
// 351.608 us; speedup vs baseline: 1.1951x; 1.1951x over previous
//
#include <hip/hip_runtime.h>
#include <math.h>

typedef unsigned short u16;
typedef __attribute__((ext_vector_type(8))) __bf16 bf16x8;
typedef __attribute__((ext_vector_type(4))) float f32x4;
typedef __attribute__((ext_vector_type(4))) u16 u16x4;
typedef __attribute__((ext_vector_type(8))) u16 u16x8;
typedef __attribute__((ext_vector_type(4))) float float4v;

constexpr int kS = 1024;
constexpr int kD = 1024;
constexpr int kDinner = 2048;
constexpr int kHeads = 32;
constexpr int kConvDim = 2176;
constexpr int kDproj = 4256;
constexpr int kDprojPad = 4352;
constexpr int kRows = 2048;   // B*S
constexpr int kHmlp = 8192;
constexpr int kHhalf = 4096;
constexpr int kL = 64;        // scan chunk length
constexpr int kNC = 16;       // chunks per sequence

__device__ __forceinline__ float bf2f(u16 u) {
    return __builtin_bit_cast(float, (unsigned int)u << 16);
}
__device__ __forceinline__ u16 f2bf(float f) {
    unsigned int u = __builtin_bit_cast(unsigned int, f);
    u += 0x7fffu + ((u >> 16) & 1u);
    return (u16)(u >> 16);
}
__device__ __forceinline__ float silu_(float x) { return x / (1.f + __expf(-x)); }

// async global->LDS, 16B per lane; LDS dest = wave-uniform base + lane*16
__device__ __forceinline__ void gld16(const u16* g, u16* l) {
    __builtin_amdgcn_global_load_lds(
        (const __attribute__((address_space(1))) void*)g,
        (__attribute__((address_space(3))) void*)l, 16, 0, 0);
}

// ---------------- fused casts: all 5 fp32->bf16 conversions in one launch ----
// fc1 is row-PERMUTED on cast so the MLP gate pair (a_p, g_p) lands in columns
// c and c+16 of the SAME lane's accumulator blocks:
//   a-row p      -> col (p>>4)*32 + (p&15)
//   g-row 4096+p -> col (p>>4)*32 + (p&15) + 16
constexpr int kB1 = kRows * kD / 4;                       // x
constexpr int kB2 = kB1 + kDprojPad * kD / 4;             // in_proj (padded)
constexpr int kB3 = kB2 + kD * kDinner / 4;               // out_proj
constexpr int kB4 = kB3 + kHmlp * kD / 4;                 // fc1 (permuted)
constexpr int kB5 = kB4 + kD * kHhalf / 4;                // fc2
__global__ __launch_bounds__(256)
void cast_all_kernel(const float* __restrict__ x, const float* __restrict__ w1,
                     const float* __restrict__ w2, const float* __restrict__ w3,
                     const float* __restrict__ w4, u16* __restrict__ xbf,
                     u16* __restrict__ w1bf, u16* __restrict__ w2bf,
                     u16* __restrict__ w3bf, u16* __restrict__ w4bf) {
    int i = blockIdx.x * 256 + threadIdx.x;
    const float* src;
    u16* dst;
    int j;
    if (i < kB1) {
        j = i; src = x; dst = xbf;
    } else if (i < kB2) {
        j = i - kB1;
        int e = j * 4, row = e >> 10, col = e & 1023;
        u16x4 o = {0, 0, 0, 0};
        if (row < kDproj) {
            float4v v = *(const float4v*)(w1 + (size_t)row * kD + col);
            o.x = f2bf(v.x); o.y = f2bf(v.y); o.z = f2bf(v.z); o.w = f2bf(v.w);
        }
        ((u16x4*)w1bf)[j] = o;
        return;
    } else if (i < kB3) {
        j = i - kB2; src = w2; dst = w2bf;
    } else if (i < kB4) {
        j = i - kB3;
        int e = j * 4, row = e >> 10, col4 = (e & 1023) >> 2;
        int p = (row < kHhalf) ? row : row - kHhalf;
        int permrow = (p >> 4) * 32 + (p & 15) + ((row < kHhalf) ? 0 : 16);
        float4v v = ((const float4v*)w3)[j];
        u16x4 o;
        o.x = f2bf(v.x); o.y = f2bf(v.y); o.z = f2bf(v.z); o.w = f2bf(v.w);
        ((u16x4*)w3bf)[permrow * 256 + col4] = o;
        return;
    } else {
        j = i - kB4; src = w4; dst = w4bf;
    }
    float4v v = ((const float4v*)src)[j];
    u16x4 o;
    o.x = f2bf(v.x); o.y = f2bf(v.y); o.z = f2bf(v.z); o.w = f2bf(v.w);
    ((u16x4*)dst)[j] = o;
}

// ---------------- GEMM: C[M,N] = A[M,K] * W[N,K]^T ----------------
// m97 staging + double-buffered LDS, one barrier per K-iter. Used for the
// small-N GEMMs (G1/G2/G4) where 256^2 tiles would under-occupy the grid.
// blockIdx.z = split-K slice (partials at Cout + z*M*N, fp32, no resid).
template <bool OUT_BF16, bool GATED = false>
__global__ __launch_bounds__(256)
void gemm_bt(const u16* __restrict__ A, const u16* __restrict__ W,
             void* __restrict__ Cout, const float* __restrict__ resid,
             int M, int N, int K) {
    __shared__ u16 As[2][128 * 32];
    __shared__ u16 Bs[2][128 * 32];
    const int tid = threadIdx.x;
    const int lane = tid & 63;
    const int w = __builtin_amdgcn_readfirstlane(tid >> 6);
    const int wm = w >> 1, wn = w & 1;
    const int bm = blockIdx.y * 128;
    const int bn = blockIdx.x * 128;
    const int z = blockIdx.z;
    const int Kchunk = K / gridDim.z;
    const int k0 = z * Kchunk;

    f32x4 acc[4][4];
#pragma unroll
    for (int i = 0; i < 4; i++)
#pragma unroll
        for (int j = 0; j < 4; j++) acc[i][j] = {0.f, 0.f, 0.f, 0.f};

    // staging: lane -> (row = lane>>2, kchunk = lane&3): global-coalesced
    const int srow = lane >> 2;          // 0..15
    const int scol = (lane & 3) * 8;     // k elem
    const u16* gA = A + (size_t)(bm + w * 32 + srow) * K + k0 + scol;
    const u16* gB = W + (size_t)(bn + w * 32 + srow) * K + k0 + scol;
    const size_t rstep = (size_t)16 * K;

    const int sbase0 = (w * 32) * 32;
    const int sbase1 = (w * 32 + 16) * 32;
    const int fra = (lane & 15) * 32 + (lane >> 4) * 8;

    // prologue: stage tile 0 into buffer 0
    gld16(gA, &As[0][sbase0]);
    gld16(gA + rstep, &As[0][sbase1]);
    gld16(gB, &Bs[0][sbase0]);
    gld16(gB + rstep, &Bs[0][sbase1]);

    const int nk = Kchunk >> 5;
    for (int i = 0; i < nk; i++) {
        const int cur = i & 1, nxt = cur ^ 1;
        __syncthreads();   // drains DMA for buf[cur]; buf[nxt] reads finished
        if (i + 1 < nk) {
            int kt2 = (i + 1) * 32;
            gld16(gA + kt2, &As[nxt][sbase0]);
            gld16(gA + kt2 + rstep, &As[nxt][sbase1]);
            gld16(gB + kt2, &Bs[nxt][sbase0]);
            gld16(gB + kt2 + rstep, &Bs[nxt][sbase1]);
        }
        bf16x8 av[4], bv[4];
#pragma unroll
        for (int mi = 0; mi < 4; mi++)
            av[mi] = *(const bf16x8*)&As[cur][(wm * 64 + mi * 16) * 32 + fra];
#pragma unroll
        for (int ni = 0; ni < 4; ni++)
            bv[ni] = *(const bf16x8*)&Bs[cur][(wn * 64 + ni * 16) * 32 + fra];
#pragma unroll
        for (int mi = 0; mi < 4; mi++)
#pragma unroll
            for (int ni = 0; ni < 4; ni++)
                acc[mi][ni] = __builtin_amdgcn_mfma_f32_16x16x32_bf16(av[mi], bv[ni], acc[mi][ni], 0, 0, 0);
    }

    const int rb = bm + wm * 64 + ((lane >> 4) << 2);
    const int cb = bn + wn * 64 + (lane & 15);
    if (GATED) {
        u16* Cb = (u16*)Cout;
        const int NG = N >> 1;
        const int gc0 = ((bn + wn * 64) >> 1) + (lane & 15);
#pragma unroll
        for (int mi = 0; mi < 4; mi++) {
#pragma unroll
            for (int p = 0; p < 2; p++) {
#pragma unroll
                for (int r = 0; r < 4; r++) {
                    float a = acc[mi][2 * p][r];
                    float g = acc[mi][2 * p + 1][r];
                    Cb[(size_t)(rb + mi * 16 + r) * NG + gc0 + p * 16] =
                        f2bf(a * silu_(g));
                }
            }
        }
        return;
    }
    float* Cf = (float*)Cout + (size_t)z * M * N;
    u16* Cb = (u16*)Cout;
#pragma unroll
    for (int mi = 0; mi < 4; mi++) {
#pragma unroll
        for (int ni = 0; ni < 4; ni++) {
#pragma unroll
            for (int r = 0; r < 4; r++) {
                size_t offo = (size_t)(rb + mi * 16 + r) * N + (cb + ni * 16);
                float v = acc[mi][ni][r];
                if (resid) v += resid[offo];
                if (OUT_BF16) Cb[offo] = f2bf(v);
                else Cf[offo] = v;
            }
        }
    }
}

// ---------------- 256x256 8-phase GEMM (gated, for G3) — v4 restored --------
// R6 post-mortem: v5's 4-wave 128x128 re-partition spilled (VGPR_Count hit
// the 256 cap; acc[8][8] f32x4 alone = 256) and 1 wave/SIMD removed all
// latency hiding -> 115 µs. v4 (8 waves, 2Mx4N, single counted vmcnt) is the
// best measured form (42.8-43.3 µs) — restored verbatim.
#define VMCNT6 asm volatile("s_waitcnt vmcnt(6)" ::: "memory")
#define VMCNT0 asm volatile("s_waitcnt vmcnt(0)" ::: "memory")

__global__ __launch_bounds__(512, 2)
void gemm256_gated(const u16* __restrict__ A, const u16* __restrict__ W,
                   u16* __restrict__ Cout, int M, int N, int K) {
    __shared__ u16 lds[2][2][2][2][4096];   // [dbuf][mat][half][kh][128*32]
    const int tid = threadIdx.x;
    const int lane = tid & 63;
    const int w = __builtin_amdgcn_readfirstlane(tid >> 6);
    const int wm = w >> 2;                  // 0..1  (M)
    const int wn = w & 3;                   // 0..3  (N)
    const int wnh = wn >> 1, wnl = wn & 1;

    // XCD-aware rectangle map (grid 8 M-tiles x 32 N-tiles = 256 blocks):
    const int lin = blockIdx.x;
    const int xcd = lin & 7, j = lin >> 3;
    const int bm = (((xcd >> 2) << 2) + (j & 3)) << 8;
    const int bn = (((xcd & 3) << 3) + (j >> 2)) << 8;

    // staging source addresses (pre-swizzled global k-slot; v2(r) XOR keeps
    // a 16-row fragment group spread 2-lanes-per-bank-quad on ds_read_b128)
    const int rst = tid >> 2, sst = tid & 3;
    const int vst = (((rst >> 1) & 1) << 1) | ((rst >> 2) & 1);
    const u16* gA0 = A + (size_t)(bm + rst) * K + ((sst ^ vst) << 3);
    const u16* gB0 = W + (size_t)(bn + rst) * K + ((sst ^ vst) << 3);
    const size_t hstep = (size_t)128 * K;
    const int wq512 = w * 512;              // wave's 1KB-block offset (elems)

    // fragment read offset (swizzled)
    const int r0a = lane & 15, slot = lane >> 4;
    const int v2a = (((r0a >> 1) & 1) << 1) | ((r0a >> 2) & 1);
    const int fro = r0a * 32 + ((slot ^ v2a) << 3);

    f32x4 acc[8][4];
#pragma unroll
    for (int i = 0; i < 8; i++)
#pragma unroll
        for (int j_ = 0; j_ < 4; j_++) acc[i][j_] = {0.f, 0.f, 0.f, 0.f};
    bf16x8 bv[4];
    const int nt = K >> 6;                  // K-tiles of 64 (>= 4 assumed)

#define STAGE(d, mat, kh, kt)                                               \
    { const u16* g_ = ((mat) ? gB0 : gA0) + (size_t)(kt) * 64 + (kh) * 32;  \
      gld16(g_, &lds[d][mat][0][kh][wq512]);                                \
      gld16(g_ + hstep, &lds[d][mat][1][kh][wq512]); }

#define LDA_FRAG(dst, d, kh, mfb)                                           \
    _Pragma("unroll") for (int i_ = 0; i_ < 4; i_++)                        \
        dst[i_] = *(const bf16x8*)&lds[d][0][wm][kh][((mfb) + i_) * 512 + fro];

#define LDB_FRAG(d, kh)                                                     \
    _Pragma("unroll") for (int i_ = 0; i_ < 4; i_++)                        \
        bv[i_] = *(const bf16x8*)&lds[d][1][wnh][kh][wnl * 2048 + i_ * 512 + fro];

#define PHASE_TAIL(g4, ...)                                                 \
    __builtin_amdgcn_s_barrier();                                           \
    asm volatile("s_waitcnt lgkmcnt(0)" ::: "memory");                      \
    __builtin_amdgcn_s_setprio(1);                                          \
    _Pragma("unroll") for (int i_ = 0; i_ < 4; i_++)                        \
        _Pragma("unroll") for (int n_ = 0; n_ < 4; n_++)                    \
            acc[(g4) * 4 + i_][n_] = __builtin_amdgcn_mfma_f32_16x16x32_bf16( \
                av[i_], bv[n_], acc[(g4) * 4 + i_][n_], 0, 0, 0);           \
    __builtin_amdgcn_s_setprio(0);                                          \
    __VA_ARGS__;                                                            \
    __builtin_amdgcn_s_barrier();

#define TILE(T, D)                                                          \
    { /* ph0: MFMA(k0, mf0-3) */                                            \
      { bf16x8 av[4]; LDB_FRAG(D, 0); LDA_FRAG(av, D, 0, 0);                \
        if ((T) + 1 < nt) STAGE(D ^ 1, 0, 1, (T) + 1);                      \
        PHASE_TAIL(0, ((void)0)) }                                          \
      /* ph1: MFMA(k0, mf4-7) */                                            \
      { bf16x8 av[4]; LDA_FRAG(av, D, 0, 4);                                \
        if ((T) + 2 < nt) STAGE(D, 1, 0, (T) + 2);                          \
        PHASE_TAIL(1, ((void)0)) }                                          \
      /* ph2: MFMA(k1, mf0-3) */                                            \
      { bf16x8 av[4]; LDB_FRAG(D, 1); LDA_FRAG(av, D, 1, 0);                \
        if ((T) + 2 < nt) STAGE(D, 0, 0, (T) + 2);                          \
        PHASE_TAIL(0, ((void)0)) }                                          \
      /* ph3: MFMA(k1, mf4-7) + the tile's single counted vmcnt */          \
      { bf16x8 av[4]; LDA_FRAG(av, D, 1, 4);                                \
        if ((T) + 2 < nt) STAGE(D, 1, 1, (T) + 2);                          \
        PHASE_TAIL(1, if ((T) + 2 < nt) { VMCNT6; }                         \
                      else if ((T) + 1 < nt) { VMCNT0; }) }                 \
    }

    // prologue: tile0 all 4 units + tile1 first 3 units (steady-state order;
    // A-k1(t1) is staged by TILE(0).ph0). vmcnt(6) waits loads 0-7 = all of
    // tile0; the 6 newest (tile1 units) stay in flight.
    STAGE(0, 1, 0, 0);   // B-k0 (t0)
    STAGE(0, 0, 0, 0);   // A-k0 (t0)
    STAGE(0, 1, 1, 0);   // B-k1 (t0)
    STAGE(0, 0, 1, 0);   // A-k1 (t0)
    STAGE(1, 1, 0, 1);   // B-k0 (t1)
    STAGE(1, 0, 0, 1);   // A-k0 (t1)
    STAGE(1, 1, 1, 1);   // B-k1 (t1)
    VMCNT6;
    __builtin_amdgcn_s_barrier();

    for (int tt = 0; tt < nt; tt += 2) {
        TILE(tt, 0)
        TILE(tt + 1, 1)
    }

#undef TILE
#undef PHASE_TAIL
#undef LDB_FRAG
#undef LDA_FRAG
#undef STAGE

    // gated epilogue: a*silu(g) -> LDS (padded rows) -> coalesced stores.
    // fc1 row-permutation puts (a,g) in nf pair (2p, 2p+1) of the same lane;
    // local gate-col = wn*32 + p*16 + (lane&15); local row = wm*128+mf*16+slot*4+r.
    __syncthreads();                       // staging LDS dead; safe to reuse
    u16* cst = (u16*)&lds[0][0][0][0][0];
    constexpr int LDE = 136;               // 272B rows: 16B-aligned, bank-spread
#pragma unroll
    for (int mf = 0; mf < 8; mf++) {
#pragma unroll
        for (int p = 0; p < 2; p++) {
#pragma unroll
            for (int r = 0; r < 4; r++) {
                float a = acc[mf][2 * p][r];
                float g = acc[mf][2 * p + 1][r];
                cst[(wm * 128 + mf * 16 + slot * 4 + r) * LDE +
                    wn * 32 + p * 16 + r0a] = f2bf(a * silu_(g));
            }
        }
    }
    __syncthreads();
    const int NG = N >> 1;
#pragma unroll
    for (int k = 0; k < 8; k++) {
        int ch = k * 512 + tid;            // 4096 chunks of 8 u16 (16B)
        int row = ch >> 4, c8 = (ch & 15) * 8;
        *(u16x8*)(Cout + (size_t)(bm + row) * NG + (bn >> 1) + c8) =
            *(const u16x8*)&cst[row * LDE + c8];
    }
}

// ---------------- split-K reduce (SK=2) + residual, fp32 out ----------------
__global__ __launch_bounds__(256)
void splitk_reduce_kernel(const float* __restrict__ Cp, const float* __restrict__ resid,
                          float* __restrict__ out, int mn4) {
    int i = blockIdx.x * 256 + threadIdx.x;
    if (i >= mn4) return;
    constexpr size_t MN = (size_t)kRows * kD;
    float4v s0 = ((const float4v*)Cp)[i];
    float4v s1 = ((const float4v*)(Cp + MN))[i];
    float4v r = ((const float4v*)resid)[i];
    float4v o;
    o.x = s0.x + s1.x + r.x;
    o.y = s0.y + s1.y + r.y;
    o.z = s0.z + s1.z + r.z;
    o.w = s0.w + s1.w + r.w;
    ((float4v*)out)[i] = o;
}

// ------- fused: split-K(2) reduce + residual + RMSNorm(1024) -> x2, xn bf16
__global__ __launch_bounds__(256)
void reduce_rms_kernel(const float* __restrict__ Cp, const float* __restrict__ resid,
                       float* __restrict__ x2, const float* __restrict__ rmsw,
                       u16* __restrict__ xnbf) {
    const int row = blockIdx.x;
    const int tid = threadIdx.x;
    constexpr size_t MN = (size_t)kRows * kD;
    size_t i = (size_t)row * (kD / 4) + tid;
    float4v s0 = ((const float4v*)Cp)[i];
    float4v s1 = ((const float4v*)(Cp + MN))[i];
    float4v r = ((const float4v*)resid)[i];
    float4v v;
    v.x = s0.x + s1.x + r.x;
    v.y = s0.y + s1.y + r.y;
    v.z = s0.z + s1.z + r.z;
    v.w = s0.w + s1.w + r.w;
    ((float4v*)x2)[i] = v;
    float ss = v.x * v.x + v.y * v.y + v.z * v.z + v.w * v.w;
#pragma unroll
    for (int off = 32; off > 0; off >>= 1) ss += __shfl_down(ss, off);
    __shared__ float red[4];
    int wv = tid >> 6, lane = tid & 63;
    if (lane == 0) red[wv] = ss;
    __syncthreads();
    ss = red[0] + red[1] + red[2] + red[3];
    float rstd = rsqrtf(ss * (1.f / kD) + 1e-5f);
    float4v wv4 = ((const float4v*)rmsw)[tid];
    u16x4 o;
    o.x = f2bf(v.x * rstd * wv4.x);
    o.y = f2bf(v.y * rstd * wv4.y);
    o.z = f2bf(v.z * rstd * wv4.z);
    o.w = f2bf(v.w * rstd * wv4.w);
    ((u16x4*)xnbf)[i] = o;
}

// ---------------- fused depthwise causal conv + silu + dt ----------------
__global__ __launch_bounds__(256)
void convdt_kernel(const u16* __restrict__ zxbf, const float* __restrict__ convw,
                   const float* __restrict__ convb, u16* __restrict__ xsbf,
                   float* __restrict__ BCf, const float* __restrict__ dt_bias,
                   float* __restrict__ dtf) {
    int c = blockIdx.x * 256 + threadIdx.x;
    int row = blockIdx.y;                 // b*1024 + s
    if (c >= kConvDim + kHeads) return;
    if (c < kConvDim) {
        int s = row & (kS - 1);
        float acc = convb[c];
#pragma unroll
        for (int j = 0; j < 4; j++) {
            int sj = s - 3 + j;
            if (sj >= 0)
                acc += bf2f(zxbf[(size_t)(row - 3 + j) * kDprojPad + kDinner + c]) * convw[c * 4 + j];
        }
        float v = silu_(acc);
        if (c < kDinner) xsbf[(size_t)row * kDinner + c] = f2bf(v);
        else BCf[(size_t)row * 128 + (c - kDinner)] = v;
    } else {
        int h = c - kConvDim;
        float raw = bf2f(zxbf[(size_t)row * kDprojPad + (kDinner + kConvDim) + h]) + dt_bias[h];
        float dt = (raw > 20.f) ? raw : log1pf(__expf(raw));
        dtf[(size_t)row * kHeads + h] = dt;
    }
}

// ---------------- Phase A: intra-chunk scan as chunked matmul (MFMA) --------
// Mamba-2 chunk form, per (b,h,chunk):
//   la[t]  = -A_h * cumsum(dt)        (log of cumulative decay a[t])
//   G      = C @ B^T                  (64x64, K=n=64)
//   M[t,s] = G[t,s]*dt_s*exp(la_t-la_s), masked s<=t
//   Y      = M @ X  (+ D*x)          (64x64, K=s=64)
//   S[p,n] = sum_s x[s,p]*dt_s*exp(la63-la_s)*B[s,n]   (chunk-end state)
// Precision: hi/lo compensated bf16 splits keep all products fp32-accurate.
__global__ __launch_bounds__(256)
void scan_chunk_kernel(const u16* __restrict__ xsbf, const float* __restrict__ BCf,
                       const float* __restrict__ dtf, const float* __restrict__ A_log,
                       const float* __restrict__ Dv, u16* __restrict__ ysbf,
                       float* __restrict__ Pf, float* __restrict__ Scf) {
    constexpr int LDT = 72;   // row stride (elems); 144B rows -> conflict-free b128
    __shared__ __align__(16) char smem[65280];
    u16* Chi  = (u16*)(smem);
    u16* Clo  = (u16*)(smem + 9216);
    u16* Bhi  = (u16*)(smem + 18432);
    u16* Blo  = (u16*)(smem + 27648);
    u16* BThi = (u16*)(smem + 36864);
    u16* BTlo = (u16*)(smem + 46080);
    u16* xT   = (u16*)(smem + 55296);
    float* laS  = (float*)(smem + 64512);
    float* dtS  = (float*)(smem + 64768);
    float* wscS = (float*)(smem + 65024);
    // overlays (all transitions barrier-separated):
    u16* Mhi  = Clo;   // Clo dead after G
    u16* Mlo  = Bhi;   // Bhi dead after G + transpose
    u16* ybuf = Chi;   // Chi dead after G

    const int c = blockIdx.x, h = blockIdx.y, b = blockIdx.z;
    const int tid = threadIdx.x;
    const int lane = tid & 63;
    const int w = __builtin_amdgcn_readfirstlane(tid >> 6);
    const int row0 = b * kS + c * kL;
    const int frow = lane & 15;
    const int fk = (lane >> 4) * 8;
    const int q4 = (lane >> 4) * 4;
    const int w16 = w * 16;

    // ---- stage B/C (hi/lo split) ----
#pragma unroll
    for (int k = 0; k < 8; k++) {
        int e4 = k * 256 + tid;              // 2048 float4s = 64 rows x 128
        int t = e4 >> 5, col = (e4 & 31) * 4;
        float4v v = *(const float4v*)(BCf + (size_t)(row0 + t) * 128 + col);
        u16x4 hi, lo;
        hi.x = f2bf(v.x); lo.x = f2bf(v.x - bf2f(hi.x));
        hi.y = f2bf(v.y); lo.y = f2bf(v.y - bf2f(hi.y));
        hi.z = f2bf(v.z); lo.z = f2bf(v.z - bf2f(hi.z));
        hi.w = f2bf(v.w); lo.w = f2bf(v.w - bf2f(hi.w));
        int cc = col & 63;
        u16* dh = (col < 64) ? Bhi : Chi;
        u16* dl = (col < 64) ? Blo : Clo;
        *(u16x4*)&dh[t * LDT + cc] = hi;
        *(u16x4*)&dl[t * LDT + cc] = lo;
    }
    // ---- stage x transposed: xT[p][t] ----
#pragma unroll
    for (int k = 0; k < 2; k++) {
        int e8 = k * 256 + tid;
        int t = e8 >> 3, p8 = (e8 & 7) * 8;
        u16x8 xv = *(const u16x8*)(xsbf + (size_t)(row0 + t) * kDinner + h * 64 + p8);
#pragma unroll
        for (int j = 0; j < 8; j++) xT[(p8 + j) * LDT + t] = xv[j];
    }
    // ---- dt load + log-decay prefix scan (wave 0) ----
    if (tid < 64) {
        float d = dtf[(size_t)(row0 + tid) * kHeads + h];
        dtS[tid] = d;
        float cs = d;
#pragma unroll
        for (int off = 1; off < 64; off <<= 1) {
            float o = __shfl_up(cs, off);
            if (lane >= off) cs += o;
        }
        float A_h = __expf(A_log[h]);
        float la = -A_h * cs;
        laS[tid] = la;
        Pf[(size_t)(row0 + tid) * kHeads + h] = __expf(la);
        float la63 = __shfl(la, 63);
        wscS[tid] = d * __expf(la63 - la);
    }
    __syncthreads();

    // ---- G = C @ B^T (only lower-triangular tile columns nt <= w) ----
    f32x4 accG[4];
#pragma unroll
    for (int i = 0; i < 4; i++) accG[i] = {0.f, 0.f, 0.f, 0.f};
#pragma unroll
    for (int kb = 0; kb < 2; kb++) {
        bf16x8 ch = *(const bf16x8*)&Chi[(w16 + frow) * LDT + kb * 32 + fk];
        bf16x8 cl = *(const bf16x8*)&Clo[(w16 + frow) * LDT + kb * 32 + fk];
#pragma unroll
        for (int nt = 0; nt < 4; nt++) {
            if (nt <= w) {
                bf16x8 bh = *(const bf16x8*)&Bhi[(nt * 16 + frow) * LDT + kb * 32 + fk];
                bf16x8 bl = *(const bf16x8*)&Blo[(nt * 16 + frow) * LDT + kb * 32 + fk];
                accG[nt] = __builtin_amdgcn_mfma_f32_16x16x32_bf16(ch, bh, accG[nt], 0, 0, 0);
                accG[nt] = __builtin_amdgcn_mfma_f32_16x16x32_bf16(ch, bl, accG[nt], 0, 0, 0);
                accG[nt] = __builtin_amdgcn_mfma_f32_16x16x32_bf16(cl, bh, accG[nt], 0, 0, 0);
            }
        }
    }
    // ---- BT transpose (for S's B-operand) ----
#pragma unroll
    for (int k = 0; k < 16; k++) {
        int e = k * 256 + tid;
        int s = e >> 6, n = e & 63;
        BThi[n * LDT + s] = Bhi[s * LDT + n];
        BTlo[n * LDT + s] = Blo[s * LDT + n];
    }
    __syncthreads();   // G reads of Clo/Bhi/Chi done -> M/ybuf overlays legal

    // ---- M build: scale G by dt_s * exp(la_t - la_s), mask, hi/lo split ----
    f32x4 la4 = *(const f32x4*)&laS[w16 + q4];
#pragma unroll
    for (int nt = 0; nt < 4; nt++) {
        int s = nt * 16 + frow;
        float las = laS[s], dts = dtS[s];
#pragma unroll
        for (int r = 0; r < 4; r++) {
            int t = w16 + q4 + r;
            float f = 0.f;
            if (nt <= w && s <= t)
                f = dts * __expf(la4[r] - las) * accG[nt][r];
            u16 mh = f2bf(f);
            u16 ml = f2bf(f - bf2f(mh));
            Mhi[t * LDT + s] = mh;
            Mlo[t * LDT + s] = ml;
        }
    }

    // ---- Y = M @ X  (per-wave own rows; same-wave LDS RAW is in-order) ----
    f32x4 accY[4];
#pragma unroll
    for (int i = 0; i < 4; i++) accY[i] = {0.f, 0.f, 0.f, 0.f};
#pragma unroll
    for (int kb = 0; kb < 2; kb++) {
        bf16x8 mh = *(const bf16x8*)&Mhi[(w16 + frow) * LDT + kb * 32 + fk];
        bf16x8 ml = *(const bf16x8*)&Mlo[(w16 + frow) * LDT + kb * 32 + fk];
#pragma unroll
        for (int nt = 0; nt < 4; nt++) {
            bf16x8 xv = *(const bf16x8*)&xT[(nt * 16 + frow) * LDT + kb * 32 + fk];
            accY[nt] = __builtin_amdgcn_mfma_f32_16x16x32_bf16(mh, xv, accY[nt], 0, 0, 0);
            accY[nt] = __builtin_amdgcn_mfma_f32_16x16x32_bf16(ml, xv, accY[nt], 0, 0, 0);
        }
    }

    // ---- S = Xw^T @ B  (Xw = x * dt * exp(la63-la), hi/lo in regs) ----
    f32x4 accS[4];
#pragma unroll
    for (int i = 0; i < 4; i++) accS[i] = {0.f, 0.f, 0.f, 0.f};
#pragma unroll
    for (int kb = 0; kb < 2; kb++) {
        u16x8 xu = __builtin_bit_cast(u16x8, *(const bf16x8*)&xT[(w16 + frow) * LDT + kb * 32 + fk]);
        f32x4 w0v = *(const f32x4*)&wscS[kb * 32 + fk];
        f32x4 w1v = *(const f32x4*)&wscS[kb * 32 + fk + 4];
        u16x8 xh, xl;
#pragma unroll
        for (int j = 0; j < 8; j++) {
            float wv = (j < 4) ? w0v[j] : w1v[j - 4];
            float f = bf2f(xu[j]) * wv;
            u16 hh = f2bf(f);
            xh[j] = hh;
            xl[j] = f2bf(f - bf2f(hh));
        }
        bf16x8 xwh = __builtin_bit_cast(bf16x8, xh);
        bf16x8 xwl = __builtin_bit_cast(bf16x8, xl);
#pragma unroll
        for (int nt = 0; nt < 4; nt++) {
            bf16x8 bh = *(const bf16x8*)&BThi[(nt * 16 + frow) * LDT + kb * 32 + fk];
            bf16x8 bl = *(const bf16x8*)&BTlo[(nt * 16 + frow) * LDT + kb * 32 + fk];
            accS[nt] = __builtin_amdgcn_mfma_f32_16x16x32_bf16(xwh, bh, accS[nt], 0, 0, 0);
            accS[nt] = __builtin_amdgcn_mfma_f32_16x16x32_bf16(xwh, bl, accS[nt], 0, 0, 0);
            accS[nt] = __builtin_amdgcn_mfma_f32_16x16x32_bf16(xwl, bh, accS[nt], 0, 0, 0);
        }
    }

    // ---- epilogue: Y += D*x -> ybuf; S -> Scf ----
    const float Dh = Dv[h];
    const int bhc = (b * 32 + h) * kNC + c;
    float* Sb = Scf + (size_t)bhc * 4096;
#pragma unroll
    for (int nt = 0; nt < 4; nt++) {
#pragma unroll
        for (int r = 0; r < 4; r++) {
            int t = w16 + q4 + r;
            int pc = nt * 16 + frow;
            float y = accY[nt][r] + Dh * bf2f(xT[pc * LDT + t]);
            ybuf[t * 64 + pc] = f2bf(y);
            Sb[t * 64 + pc] = accS[nt][r];   // t here = p-row (same index math)
        }
    }
    __syncthreads();
#pragma unroll
    for (int k = 0; k < 2; k++) {
        int e8 = k * 256 + tid;
        int t = e8 >> 3, col8 = (e8 & 7) * 8;
        *(u16x8*)(ysbf + (size_t)(row0 + t) * kDinner + h * 64 + col8) =
            *(u16x8*)&ybuf[t * 64 + col8];
    }
}

// ---------------- Phase B: sequential chunk-state combine ----------------
// 1024 blocks: recurrence serial only in c; 4096 state columns independent.
__global__ __launch_bounds__(256)
void chunk_state_kernel(const float* __restrict__ Scf, const float* __restrict__ Pf,
                        float* __restrict__ Hinf) {
    const int bh = blockIdx.x;            // 64 = (b,h)
    const int b = bh >> 5, h = bh & 31;
    const int eo = blockIdx.y * 256 + threadIdx.x;   // state elem 0..4095
    float hreg = 0.f;
    for (int c = 0; c < kNC - 1; c++) {
        float Q = Pf[(size_t)(b * kS + c * kL + kL - 1) * kHeads + h];
        hreg = Q * hreg + Scf[(size_t)(bh * kNC + c) * 4096 + eo];
        Hinf[(size_t)(bh * kNC + c + 1) * 4096 + eo] = hreg;
    }
}

// ---------------- Phase C: cross-chunk correction ----------------
__global__ __launch_bounds__(256)
void chunk_corr_kernel(const float* __restrict__ Hinf, const float* __restrict__ BCf,
                       const float* __restrict__ Pf, u16* __restrict__ ysbf) {
    const int c = blockIdx.x + 1;
    const int h = blockIdx.y, b = blockIdx.z;
    const int tid = threadIdx.x;
    const int lane = tid & 63, wq = tid >> 6;
    __shared__ float Hin_lds[64 * 65];
    __shared__ float C_lds[kL * 64];
    const int bh = b * 32 + h;
    const size_t hbase = (size_t)(bh * kNC + c) * 4096;
#pragma unroll
    for (int k = 0; k < 16; k++) {
        int e = k * 256 + tid;
        Hin_lds[(e >> 6) * 65 + (e & 63)] = Hinf[hbase + e];
    }
    const int row0 = b * kS + c * kL;
#pragma unroll
    for (int k = 0; k < 4; k++) {
        int e4 = k * 256 + tid;
        int t = e4 >> 4, n4 = (e4 & 15) * 4;
        *(float4v*)&C_lds[t * 64 + n4] =
            *(const float4v*)(BCf + (size_t)(row0 + t) * 128 + 64 + n4);
    }
    __syncthreads();

    float hr[64];
#pragma unroll
    for (int n = 0; n < 64; n++) hr[n] = Hin_lds[lane * 65 + n];

    for (int tt = 0; tt < 16; tt++) {
        int t = wq * 16 + tt;
        float corr = 0.f;
#pragma unroll
        for (int n4 = 0; n4 < 16; n4++) {
            float4v cv = *(const float4v*)&C_lds[t * 64 + n4 * 4];
            corr += cv.x * hr[n4 * 4] + cv.y * hr[n4 * 4 + 1] +
                    cv.z * hr[n4 * 4 + 2] + cv.w * hr[n4 * 4 + 3];
        }
        float Pt = Pf[(size_t)(row0 + t) * kHeads + h];
        size_t yoff = (size_t)(row0 + t) * kDinner + h * 64 + lane;
        ysbf[yoff] = f2bf(bf2f(ysbf[yoff]) + Pt * corr);
    }
}

// ---------------- gate (silu(z)) + rmsnorm over 2048 ----------------
__global__ __launch_bounds__(256)
void gatenorm_kernel(const u16* __restrict__ ysbf, const u16* __restrict__ zxbf,
                     const float* __restrict__ normw, u16* __restrict__ ybf) {
    const int row = blockIdx.x;
    const int tid = threadIdx.x;
    float v[8];
    float ss = 0.f;
#pragma unroll
    for (int i = 0; i < 8; i++) {
        int idx = i * 256 + tid;
        float y = bf2f(ysbf[(size_t)row * kDinner + idx]);
        float z = bf2f(zxbf[(size_t)row * kDprojPad + idx]);
        v[i] = y * silu_(z);
        ss += v[i] * v[i];
    }
#pragma unroll
    for (int off = 32; off > 0; off >>= 1) ss += __shfl_down(ss, off);
    __shared__ float red[4];
    int wv = tid >> 6, lane = tid & 63;
    if (lane == 0) red[wv] = ss;
    __syncthreads();
    ss = red[0] + red[1] + red[2] + red[3];
    float rstd = rsqrtf(ss * (1.f / kDinner) + 1e-5f);
#pragma unroll
    for (int i = 0; i < 8; i++) {
        int idx = i * 256 + tid;
        ybf[(size_t)row * kDinner + idx] = f2bf(v[i] * rstd * normw[idx]);
    }
}

extern "C" void kernel_launch(void* const* d_in, const int* in_sizes, int n_in,
                              void* d_out, int out_size, void* d_ws, size_t ws_size,
                              hipStream_t stream) {
    const float* x         = (const float*)d_in[0];
    const float* in_proj_w = (const float*)d_in[1];
    const float* conv_w    = (const float*)d_in[2];
    const float* conv_b    = (const float*)d_in[3];
    const float* dt_bias   = (const float*)d_in[4];
    const float* A_log     = (const float*)d_in[5];
    const float* Dvec      = (const float*)d_in[6];
    const float* ssm_norm_w= (const float*)d_in[7];
    const float* out_proj_w= (const float*)d_in[8];
    const float* rms_w     = (const float*)d_in[9];
    const float* fc1_w     = (const float*)d_in[10];
    const float* fc2_w     = (const float*)d_in[11];
    float* out = (float*)d_out;

    char* ws = (char*)d_ws;
    size_t off = 0;
    auto alloc = [&](size_t bytes) -> void* {
        void* p = ws + off;
        off += (bytes + 255) & ~(size_t)255;
        return p;
    };
    u16*   xbf  = (u16*)alloc((size_t)kRows * kD * 2);
    u16*   w1bf = (u16*)alloc((size_t)kDprojPad * kD * 2);
    u16*   w2bf = (u16*)alloc((size_t)kD * kDinner * 2);
    u16*   w3bf = (u16*)alloc((size_t)kHmlp * kD * 2);
    u16*   w4bf = (u16*)alloc((size_t)kD * kHhalf * 2);
    u16*   zxbf = (u16*)alloc((size_t)kRows * kDprojPad * 2);
    u16*   xsbf = (u16*)alloc((size_t)kRows * kDinner * 2);
    float* BCf  = (float*)alloc((size_t)kRows * 128 * 4);
    float* dtf  = (float*)alloc((size_t)kRows * kHeads * 4);
    float* Pf   = (float*)alloc((size_t)kRows * kHeads * 4);
    u16*   ysbf = (u16*)alloc((size_t)kRows * kDinner * 2);
    u16*   ybf  = (u16*)alloc((size_t)kRows * kDinner * 2);
    float* x2   = (float*)alloc((size_t)kRows * kD * 4);
    u16*   xnbf = (u16*)alloc((size_t)kRows * kD * 2);
    u16*   h1bf = (u16*)alloc((size_t)kRows * kHmlp * 2);   // scratch region
    u16*   gbf  = (u16*)alloc((size_t)kRows * kHhalf * 2);
    // Aliased scratch (h1bf region is scratch-only now):
    //   Scf/Hinf (16MB each) during scan; Cp (2*2048*1024 f32 = 16.8MB)
    //   during G2 split-K and G4 split-K.
    float* Scf  = (float*)gbf;
    float* Hinf = (float*)h1bf;
    float* Cp   = (float*)h1bf;
    (void)ws_size; (void)in_sizes; (void)n_in; (void)out_size;

    // all casts in one dispatch (fc1 row-permuted for the gated epilogue)
    cast_all_kernel<<<kB5 / 256, 256, 0, stream>>>(
        x, in_proj_w, out_proj_w, fc1_w, fc2_w, xbf, w1bf, w2bf, w3bf, w4bf);

    // G1: zxbcdt = x @ in_proj^T   (2048 x 4352, bf16 out)
    gemm_bt<true><<<dim3(kDprojPad / 128, kRows / 128, 1), 256, 0, stream>>>(
        xbf, w1bf, zxbf, nullptr, kRows, kDprojPad, kD);

    // fused conv + dt
    convdt_kernel<<<dim3((kConvDim + kHeads + 255) / 256, kRows), 256, 0, stream>>>(
        zxbf, conv_w, conv_b, xsbf, BCf, dt_bias, dtf);

    // chunked scan (Phase A MFMA chunked-matmul form)
    scan_chunk_kernel<<<dim3(kNC, kHeads, 2), 256, 0, stream>>>(
        xsbf, BCf, dtf, A_log, Dvec, ysbf, Pf, Scf);
    chunk_state_kernel<<<dim3(64, 16), 256, 0, stream>>>(Scf, Pf, Hinf);
    chunk_corr_kernel<<<dim3(kNC - 1, kHeads, 2), 256, 0, stream>>>(Hinf, BCf, Pf, ysbf);

    gatenorm_kernel<<<kRows, 256, 0, stream>>>(ysbf, zxbf, ssm_norm_w, ybf);

    // G2: x2 = y @ out_proj^T + x   (split-K=2 -> 256 blocks, then reduce+rms)
    gemm_bt<false><<<dim3(kD / 128, kRows / 128, 2), 256, 0, stream>>>(
        ybf, w2bf, Cp, nullptr, kRows, kD, kDinner);
    reduce_rms_kernel<<<kRows, 256, 0, stream>>>(Cp, x, x2, rms_w, xnbf);

    // G3+gate fused (256^2 8-phase v4): g = a*silu(g') from permuted fc1
    gemm256_gated<<<dim3((kRows >> 8) * (kHmlp >> 8)), 512, 0, stream>>>(
        xnbf, w3bf, gbf, kRows, kHmlp, kD);

    // G4: out = g @ fc2^T + x2   (split-K=2 -> 256 blocks, then reduce+resid)
    gemm_bt<false><<<dim3(kD / 128, kRows / 128, 2), 256, 0, stream>>>(
        gbf, w4bf, Cp, nullptr, kRows, kD, kHhalf);
    splitk_reduce_kernel<<<(kRows * kD / 4 + 255) / 256, 256, 0, stream>>>(
        Cp, x2, out, kRows * kD / 4);
}

// Round 8
// 340.175 us; speedup vs baseline: 1.2352x; 1.0336x over previous
//
#include <hip/hip_runtime.h>
#include <math.h>

typedef unsigned short u16;
typedef __attribute__((ext_vector_type(8))) __bf16 bf16x8;
typedef __attribute__((ext_vector_type(4))) float f32x4;
typedef __attribute__((ext_vector_type(4))) u16 u16x4;
typedef __attribute__((ext_vector_type(8))) u16 u16x8;
typedef __attribute__((ext_vector_type(4))) float float4v;

constexpr int kS = 1024;
constexpr int kD = 1024;
constexpr int kDinner = 2048;
constexpr int kHeads = 32;
constexpr int kConvDim = 2176;
constexpr int kDproj = 4256;
constexpr int kDprojPad = 4352;
constexpr int kRows = 2048;   // B*S
constexpr int kHmlp = 8192;
constexpr int kHhalf = 4096;
constexpr int kL = 64;        // scan chunk length
constexpr int kNC = 16;       // chunks per sequence

__device__ __forceinline__ float bf2f(u16 u) {
    return __builtin_bit_cast(float, (unsigned int)u << 16);
}
__device__ __forceinline__ u16 f2bf(float f) {
    unsigned int u = __builtin_bit_cast(unsigned int, f);
    u += 0x7fffu + ((u >> 16) & 1u);
    return (u16)(u >> 16);
}
__device__ __forceinline__ float silu_(float x) { return x / (1.f + __expf(-x)); }

// async global->LDS, 16B per lane; LDS dest = wave-uniform base + lane*16
__device__ __forceinline__ void gld16(const u16* g, u16* l) {
    __builtin_amdgcn_global_load_lds(
        (const __attribute__((address_space(1))) void*)g,
        (__attribute__((address_space(3))) void*)l, 16, 0, 0);
}

// ---------------- fused casts: all 5 fp32->bf16 conversions in one launch ----
// fc1 is row-PERMUTED on cast so the MLP gate pair (a_p, g_p) lands in columns
// c and c+16 of the SAME lane's accumulator blocks:
//   a-row p      -> col (p>>4)*32 + (p&15)
//   g-row 4096+p -> col (p>>4)*32 + (p&15) + 16
constexpr int kB1 = kRows * kD / 4;                       // x
constexpr int kB2 = kB1 + kDprojPad * kD / 4;             // in_proj (padded)
constexpr int kB3 = kB2 + kD * kDinner / 4;               // out_proj
constexpr int kB4 = kB3 + kHmlp * kD / 4;                 // fc1 (permuted)
constexpr int kB5 = kB4 + kD * kHhalf / 4;                // fc2
__global__ __launch_bounds__(256)
void cast_all_kernel(const float* __restrict__ x, const float* __restrict__ w1,
                     const float* __restrict__ w2, const float* __restrict__ w3,
                     const float* __restrict__ w4, u16* __restrict__ xbf,
                     u16* __restrict__ w1bf, u16* __restrict__ w2bf,
                     u16* __restrict__ w3bf, u16* __restrict__ w4bf) {
    int i = blockIdx.x * 256 + threadIdx.x;
    const float* src;
    u16* dst;
    int j;
    if (i < kB1) {
        j = i; src = x; dst = xbf;
    } else if (i < kB2) {
        j = i - kB1;
        int e = j * 4, row = e >> 10, col = e & 1023;
        u16x4 o = {0, 0, 0, 0};
        if (row < kDproj) {
            float4v v = *(const float4v*)(w1 + (size_t)row * kD + col);
            o.x = f2bf(v.x); o.y = f2bf(v.y); o.z = f2bf(v.z); o.w = f2bf(v.w);
        }
        ((u16x4*)w1bf)[j] = o;
        return;
    } else if (i < kB3) {
        j = i - kB2; src = w2; dst = w2bf;
    } else if (i < kB4) {
        j = i - kB3;
        int e = j * 4, row = e >> 10, col4 = (e & 1023) >> 2;
        int p = (row < kHhalf) ? row : row - kHhalf;
        int permrow = (p >> 4) * 32 + (p & 15) + ((row < kHhalf) ? 0 : 16);
        float4v v = ((const float4v*)w3)[j];
        u16x4 o;
        o.x = f2bf(v.x); o.y = f2bf(v.y); o.z = f2bf(v.z); o.w = f2bf(v.w);
        ((u16x4*)w3bf)[permrow * 256 + col4] = o;
        return;
    } else {
        j = i - kB4; src = w4; dst = w4bf;
    }
    float4v v = ((const float4v*)src)[j];
    u16x4 o;
    o.x = f2bf(v.x); o.y = f2bf(v.y); o.z = f2bf(v.z); o.w = f2bf(v.w);
    ((u16x4*)dst)[j] = o;
}

// ---------------- GEMM: C[M,N] = A[M,K] * W[N,K]^T ----------------
// m97 staging + double-buffered LDS, one barrier per K-iter. Used for the
// small-N GEMMs (G1/G2/G4) where 256^2 tiles would under-occupy the grid.
// blockIdx.z = split-K slice (partials at Cout + z*M*N, fp32, no resid).
// NOTE (R7 lesson): keep grid >= 2 blocks/CU — at 1 block/CU the 2-barrier
// lockstep loses its co-resident-block latency hiding (SK=2 regressed 17µs).
template <bool OUT_BF16, bool GATED = false>
__global__ __launch_bounds__(256)
void gemm_bt(const u16* __restrict__ A, const u16* __restrict__ W,
             void* __restrict__ Cout, const float* __restrict__ resid,
             int M, int N, int K) {
    __shared__ u16 As[2][128 * 32];
    __shared__ u16 Bs[2][128 * 32];
    const int tid = threadIdx.x;
    const int lane = tid & 63;
    const int w = __builtin_amdgcn_readfirstlane(tid >> 6);
    const int wm = w >> 1, wn = w & 1;
    const int bm = blockIdx.y * 128;
    const int bn = blockIdx.x * 128;
    const int z = blockIdx.z;
    const int Kchunk = K / gridDim.z;
    const int k0 = z * Kchunk;

    f32x4 acc[4][4];
#pragma unroll
    for (int i = 0; i < 4; i++)
#pragma unroll
        for (int j = 0; j < 4; j++) acc[i][j] = {0.f, 0.f, 0.f, 0.f};

    // staging: lane -> (row = lane>>2, kchunk = lane&3): global-coalesced
    const int srow = lane >> 2;          // 0..15
    const int scol = (lane & 3) * 8;     // k elem
    const u16* gA = A + (size_t)(bm + w * 32 + srow) * K + k0 + scol;
    const u16* gB = W + (size_t)(bn + w * 32 + srow) * K + k0 + scol;
    const size_t rstep = (size_t)16 * K;

    const int sbase0 = (w * 32) * 32;
    const int sbase1 = (w * 32 + 16) * 32;
    const int fra = (lane & 15) * 32 + (lane >> 4) * 8;

    // prologue: stage tile 0 into buffer 0
    gld16(gA, &As[0][sbase0]);
    gld16(gA + rstep, &As[0][sbase1]);
    gld16(gB, &Bs[0][sbase0]);
    gld16(gB + rstep, &Bs[0][sbase1]);

    const int nk = Kchunk >> 5;
    for (int i = 0; i < nk; i++) {
        const int cur = i & 1, nxt = cur ^ 1;
        __syncthreads();   // drains DMA for buf[cur]; buf[nxt] reads finished
        if (i + 1 < nk) {
            int kt2 = (i + 1) * 32;
            gld16(gA + kt2, &As[nxt][sbase0]);
            gld16(gA + kt2 + rstep, &As[nxt][sbase1]);
            gld16(gB + kt2, &Bs[nxt][sbase0]);
            gld16(gB + kt2 + rstep, &Bs[nxt][sbase1]);
        }
        bf16x8 av[4], bv[4];
#pragma unroll
        for (int mi = 0; mi < 4; mi++)
            av[mi] = *(const bf16x8*)&As[cur][(wm * 64 + mi * 16) * 32 + fra];
#pragma unroll
        for (int ni = 0; ni < 4; ni++)
            bv[ni] = *(const bf16x8*)&Bs[cur][(wn * 64 + ni * 16) * 32 + fra];
#pragma unroll
        for (int mi = 0; mi < 4; mi++)
#pragma unroll
            for (int ni = 0; ni < 4; ni++)
                acc[mi][ni] = __builtin_amdgcn_mfma_f32_16x16x32_bf16(av[mi], bv[ni], acc[mi][ni], 0, 0, 0);
    }

    const int rb = bm + wm * 64 + ((lane >> 4) << 2);
    const int cb = bn + wn * 64 + (lane & 15);
    if (GATED) {
        u16* Cb = (u16*)Cout;
        const int NG = N >> 1;
        const int gc0 = ((bn + wn * 64) >> 1) + (lane & 15);
#pragma unroll
        for (int mi = 0; mi < 4; mi++) {
#pragma unroll
            for (int p = 0; p < 2; p++) {
#pragma unroll
                for (int r = 0; r < 4; r++) {
                    float a = acc[mi][2 * p][r];
                    float g = acc[mi][2 * p + 1][r];
                    Cb[(size_t)(rb + mi * 16 + r) * NG + gc0 + p * 16] =
                        f2bf(a * silu_(g));
                }
            }
        }
        return;
    }
    float* Cf = (float*)Cout + (size_t)z * M * N;
    u16* Cb = (u16*)Cout;
#pragma unroll
    for (int mi = 0; mi < 4; mi++) {
#pragma unroll
        for (int ni = 0; ni < 4; ni++) {
#pragma unroll
            for (int r = 0; r < 4; r++) {
                size_t offo = (size_t)(rb + mi * 16 + r) * N + (cb + ni * 16);
                float v = acc[mi][ni][r];
                if (resid) v += resid[offo];
                if (OUT_BF16) Cb[offo] = f2bf(v);
                else Cf[offo] = v;
            }
        }
    }
}

// ---------------- 256x256 8-phase GEMM (gated, for G3) — v4 ----------------
// Best measured form (42.8-43.3 µs): 8 waves 2Mx4N, one counted vmcnt per
// tile, LDS-transposed coalesced epilogue, XCD rectangle map.
#define VMCNT6 asm volatile("s_waitcnt vmcnt(6)" ::: "memory")
#define VMCNT0 asm volatile("s_waitcnt vmcnt(0)" ::: "memory")

__global__ __launch_bounds__(512, 2)
void gemm256_gated(const u16* __restrict__ A, const u16* __restrict__ W,
                   u16* __restrict__ Cout, int M, int N, int K) {
    __shared__ u16 lds[2][2][2][2][4096];   // [dbuf][mat][half][kh][128*32]
    const int tid = threadIdx.x;
    const int lane = tid & 63;
    const int w = __builtin_amdgcn_readfirstlane(tid >> 6);
    const int wm = w >> 2;                  // 0..1  (M)
    const int wn = w & 3;                   // 0..3  (N)
    const int wnh = wn >> 1, wnl = wn & 1;

    // XCD-aware rectangle map (grid 8 M-tiles x 32 N-tiles = 256 blocks):
    const int lin = blockIdx.x;
    const int xcd = lin & 7, j = lin >> 3;
    const int bm = (((xcd >> 2) << 2) + (j & 3)) << 8;
    const int bn = (((xcd & 3) << 3) + (j >> 2)) << 8;

    // staging source addresses (pre-swizzled global k-slot; v2(r) XOR keeps
    // a 16-row fragment group spread 2-lanes-per-bank-quad on ds_read_b128)
    const int rst = tid >> 2, sst = tid & 3;
    const int vst = (((rst >> 1) & 1) << 1) | ((rst >> 2) & 1);
    const u16* gA0 = A + (size_t)(bm + rst) * K + ((sst ^ vst) << 3);
    const u16* gB0 = W + (size_t)(bn + rst) * K + ((sst ^ vst) << 3);
    const size_t hstep = (size_t)128 * K;
    const int wq512 = w * 512;              // wave's 1KB-block offset (elems)

    // fragment read offset (swizzled)
    const int r0a = lane & 15, slot = lane >> 4;
    const int v2a = (((r0a >> 1) & 1) << 1) | ((r0a >> 2) & 1);
    const int fro = r0a * 32 + ((slot ^ v2a) << 3);

    f32x4 acc[8][4];
#pragma unroll
    for (int i = 0; i < 8; i++)
#pragma unroll
        for (int j_ = 0; j_ < 4; j_++) acc[i][j_] = {0.f, 0.f, 0.f, 0.f};
    bf16x8 bv[4];
    const int nt = K >> 6;                  // K-tiles of 64 (>= 4 assumed)

#define STAGE(d, mat, kh, kt)                                               \
    { const u16* g_ = ((mat) ? gB0 : gA0) + (size_t)(kt) * 64 + (kh) * 32;  \
      gld16(g_, &lds[d][mat][0][kh][wq512]);                                \
      gld16(g_ + hstep, &lds[d][mat][1][kh][wq512]); }

#define LDA_FRAG(dst, d, kh, mfb)                                           \
    _Pragma("unroll") for (int i_ = 0; i_ < 4; i_++)                        \
        dst[i_] = *(const bf16x8*)&lds[d][0][wm][kh][((mfb) + i_) * 512 + fro];

#define LDB_FRAG(d, kh)                                                     \
    _Pragma("unroll") for (int i_ = 0; i_ < 4; i_++)                        \
        bv[i_] = *(const bf16x8*)&lds[d][1][wnh][kh][wnl * 2048 + i_ * 512 + fro];

#define PHASE_TAIL(g4, ...)                                                 \
    __builtin_amdgcn_s_barrier();                                           \
    asm volatile("s_waitcnt lgkmcnt(0)" ::: "memory");                      \
    __builtin_amdgcn_s_setprio(1);                                          \
    _Pragma("unroll") for (int i_ = 0; i_ < 4; i_++)                        \
        _Pragma("unroll") for (int n_ = 0; n_ < 4; n_++)                    \
            acc[(g4) * 4 + i_][n_] = __builtin_amdgcn_mfma_f32_16x16x32_bf16( \
                av[i_], bv[n_], acc[(g4) * 4 + i_][n_], 0, 0, 0);           \
    __builtin_amdgcn_s_setprio(0);                                          \
    __VA_ARGS__;                                                            \
    __builtin_amdgcn_s_barrier();

#define TILE(T, D)                                                          \
    { /* ph0: MFMA(k0, mf0-3) */                                            \
      { bf16x8 av[4]; LDB_FRAG(D, 0); LDA_FRAG(av, D, 0, 0);                \
        if ((T) + 1 < nt) STAGE(D ^ 1, 0, 1, (T) + 1);                      \
        PHASE_TAIL(0, ((void)0)) }                                          \
      /* ph1: MFMA(k0, mf4-7) */                                            \
      { bf16x8 av[4]; LDA_FRAG(av, D, 0, 4);                                \
        if ((T) + 2 < nt) STAGE(D, 1, 0, (T) + 2);                          \
        PHASE_TAIL(1, ((void)0)) }                                          \
      /* ph2: MFMA(k1, mf0-3) */                                            \
      { bf16x8 av[4]; LDB_FRAG(D, 1); LDA_FRAG(av, D, 1, 0);                \
        if ((T) + 2 < nt) STAGE(D, 0, 0, (T) + 2);                          \
        PHASE_TAIL(0, ((void)0)) }                                          \
      /* ph3: MFMA(k1, mf4-7) + the tile's single counted vmcnt */          \
      { bf16x8 av[4]; LDA_FRAG(av, D, 1, 4);                                \
        if ((T) + 2 < nt) STAGE(D, 1, 1, (T) + 2);                          \
        PHASE_TAIL(1, if ((T) + 2 < nt) { VMCNT6; }                         \
                      else if ((T) + 1 < nt) { VMCNT0; }) }                 \
    }

    // prologue: tile0 all 4 units + tile1 first 3 units (steady-state order;
    // A-k1(t1) is staged by TILE(0).ph0). vmcnt(6) waits loads 0-7 = all of
    // tile0; the 6 newest (tile1 units) stay in flight.
    STAGE(0, 1, 0, 0);   // B-k0 (t0)
    STAGE(0, 0, 0, 0);   // A-k0 (t0)
    STAGE(0, 1, 1, 0);   // B-k1 (t0)
    STAGE(0, 0, 1, 0);   // A-k1 (t0)
    STAGE(1, 1, 0, 1);   // B-k0 (t1)
    STAGE(1, 0, 0, 1);   // A-k0 (t1)
    STAGE(1, 1, 1, 1);   // B-k1 (t1)
    VMCNT6;
    __builtin_amdgcn_s_barrier();

    for (int tt = 0; tt < nt; tt += 2) {
        TILE(tt, 0)
        TILE(tt + 1, 1)
    }

#undef TILE
#undef PHASE_TAIL
#undef LDB_FRAG
#undef LDA_FRAG
#undef STAGE

    // gated epilogue: a*silu(g) -> LDS (padded rows) -> coalesced stores.
    // fc1 row-permutation puts (a,g) in nf pair (2p, 2p+1) of the same lane;
    // local gate-col = wn*32 + p*16 + (lane&15); local row = wm*128+mf*16+slot*4+r.
    __syncthreads();                       // staging LDS dead; safe to reuse
    u16* cst = (u16*)&lds[0][0][0][0][0];
    constexpr int LDE = 136;               // 272B rows: 16B-aligned, bank-spread
#pragma unroll
    for (int mf = 0; mf < 8; mf++) {
#pragma unroll
        for (int p = 0; p < 2; p++) {
#pragma unroll
            for (int r = 0; r < 4; r++) {
                float a = acc[mf][2 * p][r];
                float g = acc[mf][2 * p + 1][r];
                cst[(wm * 128 + mf * 16 + slot * 4 + r) * LDE +
                    wn * 32 + p * 16 + r0a] = f2bf(a * silu_(g));
            }
        }
    }
    __syncthreads();
    const int NG = N >> 1;
#pragma unroll
    for (int k = 0; k < 8; k++) {
        int ch = k * 512 + tid;            // 4096 chunks of 8 u16 (16B)
        int row = ch >> 4, c8 = (ch & 15) * 8;
        *(u16x8*)(Cout + (size_t)(bm + row) * NG + (bn >> 1) + c8) =
            *(const u16x8*)&cst[row * LDE + c8];
    }
}

// ---------------- split-K reduce (SK=4) + residual, fp32 out ----------------
__global__ __launch_bounds__(256)
void splitk_reduce_kernel(const float* __restrict__ Cp, const float* __restrict__ resid,
                          float* __restrict__ out, int mn4) {
    int i = blockIdx.x * 256 + threadIdx.x;
    if (i >= mn4) return;
    constexpr size_t MN = (size_t)kRows * kD;
    float4v s0 = ((const float4v*)Cp)[i];
    float4v s1 = ((const float4v*)(Cp + MN))[i];
    float4v s2 = ((const float4v*)(Cp + 2 * MN))[i];
    float4v s3 = ((const float4v*)(Cp + 3 * MN))[i];
    float4v r = ((const float4v*)resid)[i];
    float4v o;
    o.x = s0.x + s1.x + s2.x + s3.x + r.x;
    o.y = s0.y + s1.y + s2.y + s3.y + r.y;
    o.z = s0.z + s1.z + s2.z + s3.z + r.z;
    o.w = s0.w + s1.w + s2.w + s3.w + r.w;
    ((float4v*)out)[i] = o;
}

// ------- fused: split-K(4) reduce + residual + RMSNorm(1024) -> x2, xn bf16
__global__ __launch_bounds__(256)
void reduce_rms_kernel(const float* __restrict__ Cp, const float* __restrict__ resid,
                       float* __restrict__ x2, const float* __restrict__ rmsw,
                       u16* __restrict__ xnbf) {
    const int row = blockIdx.x;
    const int tid = threadIdx.x;
    constexpr size_t MN = (size_t)kRows * kD;
    size_t i = (size_t)row * (kD / 4) + tid;
    float4v s0 = ((const float4v*)Cp)[i];
    float4v s1 = ((const float4v*)(Cp + MN))[i];
    float4v s2 = ((const float4v*)(Cp + 2 * MN))[i];
    float4v s3 = ((const float4v*)(Cp + 3 * MN))[i];
    float4v r = ((const float4v*)resid)[i];
    float4v v;
    v.x = s0.x + s1.x + s2.x + s3.x + r.x;
    v.y = s0.y + s1.y + s2.y + s3.y + r.y;
    v.z = s0.z + s1.z + s2.z + s3.z + r.z;
    v.w = s0.w + s1.w + s2.w + s3.w + r.w;
    ((float4v*)x2)[i] = v;
    float ss = v.x * v.x + v.y * v.y + v.z * v.z + v.w * v.w;
#pragma unroll
    for (int off = 32; off > 0; off >>= 1) ss += __shfl_down(ss, off);
    __shared__ float red[4];
    int wv = tid >> 6, lane = tid & 63;
    if (lane == 0) red[wv] = ss;
    __syncthreads();
    ss = red[0] + red[1] + red[2] + red[3];
    float rstd = rsqrtf(ss * (1.f / kD) + 1e-5f);
    float4v wv4 = ((const float4v*)rmsw)[tid];
    u16x4 o;
    o.x = f2bf(v.x * rstd * wv4.x);
    o.y = f2bf(v.y * rstd * wv4.y);
    o.z = f2bf(v.z * rstd * wv4.z);
    o.w = f2bf(v.w * rstd * wv4.w);
    ((u16x4*)xnbf)[i] = o;
}

// ---------------- fused depthwise causal conv + silu + dt ----------------
__global__ __launch_bounds__(256)
void convdt_kernel(const u16* __restrict__ zxbf, const float* __restrict__ convw,
                   const float* __restrict__ convb, u16* __restrict__ xsbf,
                   float* __restrict__ BCf, const float* __restrict__ dt_bias,
                   float* __restrict__ dtf) {
    int c = blockIdx.x * 256 + threadIdx.x;
    int row = blockIdx.y;                 // b*1024 + s
    if (c >= kConvDim + kHeads) return;
    if (c < kConvDim) {
        int s = row & (kS - 1);
        float acc = convb[c];
#pragma unroll
        for (int j = 0; j < 4; j++) {
            int sj = s - 3 + j;
            if (sj >= 0)
                acc += bf2f(zxbf[(size_t)(row - 3 + j) * kDprojPad + kDinner + c]) * convw[c * 4 + j];
        }
        float v = silu_(acc);
        if (c < kDinner) xsbf[(size_t)row * kDinner + c] = f2bf(v);
        else BCf[(size_t)row * 128 + (c - kDinner)] = v;
    } else {
        int h = c - kConvDim;
        float raw = bf2f(zxbf[(size_t)row * kDprojPad + (kDinner + kConvDim) + h]) + dt_bias[h];
        float dt = (raw > 20.f) ? raw : log1pf(__expf(raw));
        dtf[(size_t)row * kHeads + h] = dt;
    }
}

// ---------------- Phase A: intra-chunk scan as chunked matmul (MFMA) --------
// Mamba-2 chunk form, per (b,h,chunk):
//   la[t]  = -A_h * cumsum(dt)        (log of cumulative decay a[t])
//   G      = C @ B^T                  (64x64, K=n=64)
//   M[t,s] = G[t,s]*dt_s*exp(la_t-la_s), masked s<=t
//   Y      = M @ X  (+ D*x)          (64x64, K=s=64)
//   S[p,n] = sum_s x[s,p]*dt_s*exp(la63-la_s)*B[s,n]   (chunk-end state)
// Precision: hi/lo compensated bf16 splits keep all products fp32-accurate.
__global__ __launch_bounds__(256)
void scan_chunk_kernel(const u16* __restrict__ xsbf, const float* __restrict__ BCf,
                       const float* __restrict__ dtf, const float* __restrict__ A_log,
                       const float* __restrict__ Dv, u16* __restrict__ ysbf,
                       float* __restrict__ Pf, float* __restrict__ Scf) {
    constexpr int LDT = 72;   // row stride (elems); 144B rows -> conflict-free b128
    __shared__ __align__(16) char smem[65280];
    u16* Chi  = (u16*)(smem);
    u16* Clo  = (u16*)(smem + 9216);
    u16* Bhi  = (u16*)(smem + 18432);
    u16* Blo  = (u16*)(smem + 27648);
    u16* BThi = (u16*)(smem + 36864);
    u16* BTlo = (u16*)(smem + 46080);
    u16* xT   = (u16*)(smem + 55296);
    float* laS  = (float*)(smem + 64512);
    float* dtS  = (float*)(smem + 64768);
    float* wscS = (float*)(smem + 65024);
    // overlays (all transitions barrier-separated):
    u16* Mhi  = Clo;   // Clo dead after G
    u16* Mlo  = Bhi;   // Bhi dead after G + transpose
    u16* ybuf = Chi;   // Chi dead after G

    const int c = blockIdx.x, h = blockIdx.y, b = blockIdx.z;
    const int tid = threadIdx.x;
    const int lane = tid & 63;
    const int w = __builtin_amdgcn_readfirstlane(tid >> 6);
    const int row0 = b * kS + c * kL;
    const int frow = lane & 15;
    const int fk = (lane >> 4) * 8;
    const int q4 = (lane >> 4) * 4;
    const int w16 = w * 16;

    // ---- stage B/C (hi/lo split) ----
#pragma unroll
    for (int k = 0; k < 8; k++) {
        int e4 = k * 256 + tid;              // 2048 float4s = 64 rows x 128
        int t = e4 >> 5, col = (e4 & 31) * 4;
        float4v v = *(const float4v*)(BCf + (size_t)(row0 + t) * 128 + col);
        u16x4 hi, lo;
        hi.x = f2bf(v.x); lo.x = f2bf(v.x - bf2f(hi.x));
        hi.y = f2bf(v.y); lo.y = f2bf(v.y - bf2f(hi.y));
        hi.z = f2bf(v.z); lo.z = f2bf(v.z - bf2f(hi.z));
        hi.w = f2bf(v.w); lo.w = f2bf(v.w - bf2f(hi.w));
        int cc = col & 63;
        u16* dh = (col < 64) ? Bhi : Chi;
        u16* dl = (col < 64) ? Blo : Clo;
        *(u16x4*)&dh[t * LDT + cc] = hi;
        *(u16x4*)&dl[t * LDT + cc] = lo;
    }
    // ---- stage x transposed: xT[p][t] ----
#pragma unroll
    for (int k = 0; k < 2; k++) {
        int e8 = k * 256 + tid;
        int t = e8 >> 3, p8 = (e8 & 7) * 8;
        u16x8 xv = *(const u16x8*)(xsbf + (size_t)(row0 + t) * kDinner + h * 64 + p8);
#pragma unroll
        for (int j = 0; j < 8; j++) xT[(p8 + j) * LDT + t] = xv[j];
    }
    // ---- dt load + log-decay prefix scan (wave 0) ----
    if (tid < 64) {
        float d = dtf[(size_t)(row0 + tid) * kHeads + h];
        dtS[tid] = d;
        float cs = d;
#pragma unroll
        for (int off = 1; off < 64; off <<= 1) {
            float o = __shfl_up(cs, off);
            if (lane >= off) cs += o;
        }
        float A_h = __expf(A_log[h]);
        float la = -A_h * cs;
        laS[tid] = la;
        Pf[(size_t)(row0 + tid) * kHeads + h] = __expf(la);
        float la63 = __shfl(la, 63);
        wscS[tid] = d * __expf(la63 - la);
    }
    __syncthreads();

    // ---- G = C @ B^T (only lower-triangular tile columns nt <= w) ----
    f32x4 accG[4];
#pragma unroll
    for (int i = 0; i < 4; i++) accG[i] = {0.f, 0.f, 0.f, 0.f};
#pragma unroll
    for (int kb = 0; kb < 2; kb++) {
        bf16x8 ch = *(const bf16x8*)&Chi[(w16 + frow) * LDT + kb * 32 + fk];
        bf16x8 cl = *(const bf16x8*)&Clo[(w16 + frow) * LDT + kb * 32 + fk];
#pragma unroll
        for (int nt = 0; nt < 4; nt++) {
            if (nt <= w) {
                bf16x8 bh = *(const bf16x8*)&Bhi[(nt * 16 + frow) * LDT + kb * 32 + fk];
                bf16x8 bl = *(const bf16x8*)&Blo[(nt * 16 + frow) * LDT + kb * 32 + fk];
                accG[nt] = __builtin_amdgcn_mfma_f32_16x16x32_bf16(ch, bh, accG[nt], 0, 0, 0);
                accG[nt] = __builtin_amdgcn_mfma_f32_16x16x32_bf16(ch, bl, accG[nt], 0, 0, 0);
                accG[nt] = __builtin_amdgcn_mfma_f32_16x16x32_bf16(cl, bh, accG[nt], 0, 0, 0);
            }
        }
    }
    // ---- BT transpose (for S's B-operand) ----
#pragma unroll
    for (int k = 0; k < 16; k++) {
        int e = k * 256 + tid;
        int s = e >> 6, n = e & 63;
        BThi[n * LDT + s] = Bhi[s * LDT + n];
        BTlo[n * LDT + s] = Blo[s * LDT + n];
    }
    __syncthreads();   // G reads of Clo/Bhi/Chi done -> M/ybuf overlays legal

    // ---- M build: scale G by dt_s * exp(la_t - la_s), mask, hi/lo split ----
    f32x4 la4 = *(const f32x4*)&laS[w16 + q4];
#pragma unroll
    for (int nt = 0; nt < 4; nt++) {
        int s = nt * 16 + frow;
        float las = laS[s], dts = dtS[s];
#pragma unroll
        for (int r = 0; r < 4; r++) {
            int t = w16 + q4 + r;
            float f = 0.f;
            if (nt <= w && s <= t)
                f = dts * __expf(la4[r] - las) * accG[nt][r];
            u16 mh = f2bf(f);
            u16 ml = f2bf(f - bf2f(mh));
            Mhi[t * LDT + s] = mh;
            Mlo[t * LDT + s] = ml;
        }
    }

    // ---- Y = M @ X  (per-wave own rows; same-wave LDS RAW is in-order) ----
    f32x4 accY[4];
#pragma unroll
    for (int i = 0; i < 4; i++) accY[i] = {0.f, 0.f, 0.f, 0.f};
#pragma unroll
    for (int kb = 0; kb < 2; kb++) {
        bf16x8 mh = *(const bf16x8*)&Mhi[(w16 + frow) * LDT + kb * 32 + fk];
        bf16x8 ml = *(const bf16x8*)&Mlo[(w16 + frow) * LDT + kb * 32 + fk];
#pragma unroll
        for (int nt = 0; nt < 4; nt++) {
            bf16x8 xv = *(const bf16x8*)&xT[(nt * 16 + frow) * LDT + kb * 32 + fk];
            accY[nt] = __builtin_amdgcn_mfma_f32_16x16x32_bf16(mh, xv, accY[nt], 0, 0, 0);
            accY[nt] = __builtin_amdgcn_mfma_f32_16x16x32_bf16(ml, xv, accY[nt], 0, 0, 0);
        }
    }

    // ---- S = Xw^T @ B  (Xw = x * dt * exp(la63-la), hi/lo in regs) ----
    f32x4 accS[4];
#pragma unroll
    for (int i = 0; i < 4; i++) accS[i] = {0.f, 0.f, 0.f, 0.f};
#pragma unroll
    for (int kb = 0; kb < 2; kb++) {
        u16x8 xu = __builtin_bit_cast(u16x8, *(const bf16x8*)&xT[(w16 + frow) * LDT + kb * 32 + fk]);
        f32x4 w0v = *(const f32x4*)&wscS[kb * 32 + fk];
        f32x4 w1v = *(const f32x4*)&wscS[kb * 32 + fk + 4];
        u16x8 xh, xl;
#pragma unroll
        for (int j = 0; j < 8; j++) {
            float wv = (j < 4) ? w0v[j] : w1v[j - 4];
            float f = bf2f(xu[j]) * wv;
            u16 hh = f2bf(f);
            xh[j] = hh;
            xl[j] = f2bf(f - bf2f(hh));
        }
        bf16x8 xwh = __builtin_bit_cast(bf16x8, xh);
        bf16x8 xwl = __builtin_bit_cast(bf16x8, xl);
#pragma unroll
        for (int nt = 0; nt < 4; nt++) {
            bf16x8 bh = *(const bf16x8*)&BThi[(nt * 16 + frow) * LDT + kb * 32 + fk];
            bf16x8 bl = *(const bf16x8*)&BTlo[(nt * 16 + frow) * LDT + kb * 32 + fk];
            accS[nt] = __builtin_amdgcn_mfma_f32_16x16x32_bf16(xwh, bh, accS[nt], 0, 0, 0);
            accS[nt] = __builtin_amdgcn_mfma_f32_16x16x32_bf16(xwh, bl, accS[nt], 0, 0, 0);
            accS[nt] = __builtin_amdgcn_mfma_f32_16x16x32_bf16(xwl, bh, accS[nt], 0, 0, 0);
        }
    }

    // ---- epilogue: Y += D*x -> ybuf; S -> Scf ----
    const float Dh = Dv[h];
    const int bhc = (b * 32 + h) * kNC + c;
    float* Sb = Scf + (size_t)bhc * 4096;
#pragma unroll
    for (int nt = 0; nt < 4; nt++) {
#pragma unroll
        for (int r = 0; r < 4; r++) {
            int t = w16 + q4 + r;
            int pc = nt * 16 + frow;
            float y = accY[nt][r] + Dh * bf2f(xT[pc * LDT + t]);
            ybuf[t * 64 + pc] = f2bf(y);
            Sb[t * 64 + pc] = accS[nt][r];   // t here = p-row (same index math)
        }
    }
    __syncthreads();
#pragma unroll
    for (int k = 0; k < 2; k++) {
        int e8 = k * 256 + tid;
        int t = e8 >> 3, col8 = (e8 & 7) * 8;
        *(u16x8*)(ysbf + (size_t)(row0 + t) * kDinner + h * 64 + col8) =
            *(u16x8*)&ybuf[t * 64 + col8];
    }
}

// ---------------- Phase B: sequential chunk-state combine ----------------
// 1024 blocks: recurrence serial only in c; 4096 state columns independent.
__global__ __launch_bounds__(256)
void chunk_state_kernel(const float* __restrict__ Scf, const float* __restrict__ Pf,
                        float* __restrict__ Hinf) {
    const int bh = blockIdx.x;            // 64 = (b,h)
    const int b = bh >> 5, h = bh & 31;
    const int eo = blockIdx.y * 256 + threadIdx.x;   // state elem 0..4095
    float hreg = 0.f;
    for (int c = 0; c < kNC - 1; c++) {
        float Q = Pf[(size_t)(b * kS + c * kL + kL - 1) * kHeads + h];
        hreg = Q * hreg + Scf[(size_t)(bh * kNC + c) * 4096 + eo];
        Hinf[(size_t)(bh * kNC + c + 1) * 4096 + eo] = hreg;
    }
}

// ---------------- Phase C: cross-chunk correction ----------------
__global__ __launch_bounds__(256)
void chunk_corr_kernel(const float* __restrict__ Hinf, const float* __restrict__ BCf,
                       const float* __restrict__ Pf, u16* __restrict__ ysbf) {
    const int c = blockIdx.x + 1;
    const int h = blockIdx.y, b = blockIdx.z;
    const int tid = threadIdx.x;
    const int lane = tid & 63, wq = tid >> 6;
    __shared__ float Hin_lds[64 * 65];
    __shared__ float C_lds[kL * 64];
    const int bh = b * 32 + h;
    const size_t hbase = (size_t)(bh * kNC + c) * 4096;
#pragma unroll
    for (int k = 0; k < 16; k++) {
        int e = k * 256 + tid;
        Hin_lds[(e >> 6) * 65 + (e & 63)] = Hinf[hbase + e];
    }
    const int row0 = b * kS + c * kL;
#pragma unroll
    for (int k = 0; k < 4; k++) {
        int e4 = k * 256 + tid;
        int t = e4 >> 4, n4 = (e4 & 15) * 4;
        *(float4v*)&C_lds[t * 64 + n4] =
            *(const float4v*)(BCf + (size_t)(row0 + t) * 128 + 64 + n4);
    }
    __syncthreads();

    float hr[64];
#pragma unroll
    for (int n = 0; n < 64; n++) hr[n] = Hin_lds[lane * 65 + n];

    for (int tt = 0; tt < 16; tt++) {
        int t = wq * 16 + tt;
        float corr = 0.f;
#pragma unroll
        for (int n4 = 0; n4 < 16; n4++) {
            float4v cv = *(const float4v*)&C_lds[t * 64 + n4 * 4];
            corr += cv.x * hr[n4 * 4] + cv.y * hr[n4 * 4 + 1] +
                    cv.z * hr[n4 * 4 + 2] + cv.w * hr[n4 * 4 + 3];
        }
        float Pt = Pf[(size_t)(row0 + t) * kHeads + h];
        size_t yoff = (size_t)(row0 + t) * kDinner + h * 64 + lane;
        ysbf[yoff] = f2bf(bf2f(ysbf[yoff]) + Pt * corr);
    }
}

// ---------------- gate (silu(z)) + rmsnorm over 2048 ----------------
__global__ __launch_bounds__(256)
void gatenorm_kernel(const u16* __restrict__ ysbf, const u16* __restrict__ zxbf,
                     const float* __restrict__ normw, u16* __restrict__ ybf) {
    const int row = blockIdx.x;
    const int tid = threadIdx.x;
    float v[8];
    float ss = 0.f;
#pragma unroll
    for (int i = 0; i < 8; i++) {
        int idx = i * 256 + tid;
        float y = bf2f(ysbf[(size_t)row * kDinner + idx]);
        float z = bf2f(zxbf[(size_t)row * kDprojPad + idx]);
        v[i] = y * silu_(z);
        ss += v[i] * v[i];
    }
#pragma unroll
    for (int off = 32; off > 0; off >>= 1) ss += __shfl_down(ss, off);
    __shared__ float red[4];
    int wv = tid >> 6, lane = tid & 63;
    if (lane == 0) red[wv] = ss;
    __syncthreads();
    ss = red[0] + red[1] + red[2] + red[3];
    float rstd = rsqrtf(ss * (1.f / kDinner) + 1e-5f);
#pragma unroll
    for (int i = 0; i < 8; i++) {
        int idx = i * 256 + tid;
        ybf[(size_t)row * kDinner + idx] = f2bf(v[i] * rstd * normw[idx]);
    }
}

extern "C" void kernel_launch(void* const* d_in, const int* in_sizes, int n_in,
                              void* d_out, int out_size, void* d_ws, size_t ws_size,
                              hipStream_t stream) {
    const float* x         = (const float*)d_in[0];
    const float* in_proj_w = (const float*)d_in[1];
    const float* conv_w    = (const float*)d_in[2];
    const float* conv_b    = (const float*)d_in[3];
    const float* dt_bias   = (const float*)d_in[4];
    const float* A_log     = (const float*)d_in[5];
    const float* Dvec      = (const float*)d_in[6];
    const float* ssm_norm_w= (const float*)d_in[7];
    const float* out_proj_w= (const float*)d_in[8];
    const float* rms_w     = (const float*)d_in[9];
    const float* fc1_w     = (const float*)d_in[10];
    const float* fc2_w     = (const float*)d_in[11];
    float* out = (float*)d_out;

    char* ws = (char*)d_ws;
    size_t off = 0;
    auto alloc = [&](size_t bytes) -> void* {
        void* p = ws + off;
        off += (bytes + 255) & ~(size_t)255;
        return p;
    };
    u16*   xbf  = (u16*)alloc((size_t)kRows * kD * 2);
    u16*   w1bf = (u16*)alloc((size_t)kDprojPad * kD * 2);
    u16*   w2bf = (u16*)alloc((size_t)kD * kDinner * 2);
    u16*   w3bf = (u16*)alloc((size_t)kHmlp * kD * 2);
    u16*   w4bf = (u16*)alloc((size_t)kD * kHhalf * 2);
    u16*   zxbf = (u16*)alloc((size_t)kRows * kDprojPad * 2);
    u16*   xsbf = (u16*)alloc((size_t)kRows * kDinner * 2);
    float* BCf  = (float*)alloc((size_t)kRows * 128 * 4);
    float* dtf  = (float*)alloc((size_t)kRows * kHeads * 4);
    float* Pf   = (float*)alloc((size_t)kRows * kHeads * 4);
    u16*   ysbf = (u16*)alloc((size_t)kRows * kDinner * 2);
    u16*   ybf  = (u16*)alloc((size_t)kRows * kDinner * 2);
    float* x2   = (float*)alloc((size_t)kRows * kD * 4);
    u16*   xnbf = (u16*)alloc((size_t)kRows * kD * 2);
    u16*   h1bf = (u16*)alloc((size_t)kRows * kHmlp * 2);   // scratch region
    u16*   gbf  = (u16*)alloc((size_t)kRows * kHhalf * 2);
    // Aliased scratch (h1bf region is scratch-only now):
    //   Scf/Hinf (16MB each) during scan; Cp (4*2048*1024 f32 = 33.55MB)
    //   during G2 split-K and G4 split-K.
    float* Scf  = (float*)gbf;
    float* Hinf = (float*)h1bf;
    float* Cp   = (float*)h1bf;
    (void)ws_size; (void)in_sizes; (void)n_in; (void)out_size;

    // all casts in one dispatch (fc1 row-permuted for the gated epilogue)
    cast_all_kernel<<<kB5 / 256, 256, 0, stream>>>(
        x, in_proj_w, out_proj_w, fc1_w, fc2_w, xbf, w1bf, w2bf, w3bf, w4bf);

    // G1: zxbcdt = x @ in_proj^T   (2048 x 4352, bf16 out)
    gemm_bt<true><<<dim3(kDprojPad / 128, kRows / 128, 1), 256, 0, stream>>>(
        xbf, w1bf, zxbf, nullptr, kRows, kDprojPad, kD);

    // fused conv + dt
    convdt_kernel<<<dim3((kConvDim + kHeads + 255) / 256, kRows), 256, 0, stream>>>(
        zxbf, conv_w, conv_b, xsbf, BCf, dt_bias, dtf);

    // chunked scan (Phase A MFMA chunked-matmul form)
    scan_chunk_kernel<<<dim3(kNC, kHeads, 2), 256, 0, stream>>>(
        xsbf, BCf, dtf, A_log, Dvec, ysbf, Pf, Scf);
    chunk_state_kernel<<<dim3(64, 16), 256, 0, stream>>>(Scf, Pf, Hinf);
    chunk_corr_kernel<<<dim3(kNC - 1, kHeads, 2), 256, 0, stream>>>(Hinf, BCf, Pf, ysbf);

    gatenorm_kernel<<<kRows, 256, 0, stream>>>(ysbf, zxbf, ssm_norm_w, ybf);

    // G2: x2 = y @ out_proj^T + x   (split-K=4 -> 512 blocks = 2/CU, proven)
    gemm_bt<false><<<dim3(kD / 128, kRows / 128, 4), 256, 0, stream>>>(
        ybf, w2bf, Cp, nullptr, kRows, kD, kDinner);
    reduce_rms_kernel<<<kRows, 256, 0, stream>>>(Cp, x, x2, rms_w, xnbf);

    // G3+gate fused (256^2 8-phase v4): g = a*silu(g') from permuted fc1
    gemm256_gated<<<dim3((kRows >> 8) * (kHmlp >> 8)), 512, 0, stream>>>(
        xnbf, w3bf, gbf, kRows, kHmlp, kD);

    // G4: out = g @ fc2^T + x2   (split-K=4 -> 512 blocks = 2/CU, proven)
    gemm_bt<false><<<dim3(kD / 128, kRows / 128, 4), 256, 0, stream>>>(
        gbf, w4bf, Cp, nullptr, kRows, kD, kHhalf);
    splitk_reduce_kernel<<<(kRows * kD / 4 + 255) / 256, 256, 0, stream>>>(
        Cp, x2, out, kRows * kD / 4);
}

// Round 9
// 332.826 us; speedup vs baseline: 1.2625x; 1.0221x over previous
//
#include <hip/hip_runtime.h>
#include <math.h>

typedef unsigned short u16;
typedef __attribute__((ext_vector_type(8))) __bf16 bf16x8;
typedef __attribute__((ext_vector_type(4))) float f32x4;
typedef __attribute__((ext_vector_type(4))) u16 u16x4;
typedef __attribute__((ext_vector_type(8))) u16 u16x8;
typedef __attribute__((ext_vector_type(4))) float float4v;

constexpr int kS = 1024;
constexpr int kD = 1024;
constexpr int kDinner = 2048;
constexpr int kHeads = 32;
constexpr int kConvDim = 2176;
constexpr int kDproj = 4256;
constexpr int kDprojPad = 4352;
constexpr int kRows = 2048;   // B*S
constexpr int kHmlp = 8192;
constexpr int kHhalf = 4096;
constexpr int kL = 64;        // scan chunk length
constexpr int kNC = 16;       // chunks per sequence

__device__ __forceinline__ float bf2f(u16 u) {
    return __builtin_bit_cast(float, (unsigned int)u << 16);
}
__device__ __forceinline__ u16 f2bf(float f) {
    unsigned int u = __builtin_bit_cast(unsigned int, f);
    u += 0x7fffu + ((u >> 16) & 1u);
    return (u16)(u >> 16);
}
__device__ __forceinline__ float silu_(float x) { return x / (1.f + __expf(-x)); }

// async global->LDS, 16B per lane; LDS dest = wave-uniform base + lane*16
__device__ __forceinline__ void gld16(const u16* g, u16* l) {
    __builtin_amdgcn_global_load_lds(
        (const __attribute__((address_space(1))) void*)g,
        (__attribute__((address_space(3))) void*)l, 16, 0, 0);
}

// ---------------- fused casts: all 5 fp32->bf16 conversions in one launch ----
// fc1 is row-PERMUTED on cast so the MLP gate pair (a_p, g_p) lands in columns
// c and c+16 of the SAME lane's accumulator blocks:
//   a-row p      -> col (p>>4)*32 + (p&15)
//   g-row 4096+p -> col (p>>4)*32 + (p&15) + 16
constexpr int kB1 = kRows * kD / 4;                       // x
constexpr int kB2 = kB1 + kDprojPad * kD / 4;             // in_proj (padded)
constexpr int kB3 = kB2 + kD * kDinner / 4;               // out_proj
constexpr int kB4 = kB3 + kHmlp * kD / 4;                 // fc1 (permuted)
constexpr int kB5 = kB4 + kD * kHhalf / 4;                // fc2
__global__ __launch_bounds__(256)
void cast_all_kernel(const float* __restrict__ x, const float* __restrict__ w1,
                     const float* __restrict__ w2, const float* __restrict__ w3,
                     const float* __restrict__ w4, u16* __restrict__ xbf,
                     u16* __restrict__ w1bf, u16* __restrict__ w2bf,
                     u16* __restrict__ w3bf, u16* __restrict__ w4bf) {
    int i = blockIdx.x * 256 + threadIdx.x;
    const float* src;
    u16* dst;
    int j;
    if (i < kB1) {
        j = i; src = x; dst = xbf;
    } else if (i < kB2) {
        j = i - kB1;
        int e = j * 4, row = e >> 10, col = e & 1023;
        u16x4 o = {0, 0, 0, 0};
        if (row < kDproj) {
            float4v v = *(const float4v*)(w1 + (size_t)row * kD + col);
            o.x = f2bf(v.x); o.y = f2bf(v.y); o.z = f2bf(v.z); o.w = f2bf(v.w);
        }
        ((u16x4*)w1bf)[j] = o;
        return;
    } else if (i < kB3) {
        j = i - kB2; src = w2; dst = w2bf;
    } else if (i < kB4) {
        j = i - kB3;
        int e = j * 4, row = e >> 10, col4 = (e & 1023) >> 2;
        int p = (row < kHhalf) ? row : row - kHhalf;
        int permrow = (p >> 4) * 32 + (p & 15) + ((row < kHhalf) ? 0 : 16);
        float4v v = ((const float4v*)w3)[j];
        u16x4 o;
        o.x = f2bf(v.x); o.y = f2bf(v.y); o.z = f2bf(v.z); o.w = f2bf(v.w);
        ((u16x4*)w3bf)[permrow * 256 + col4] = o;
        return;
    } else {
        j = i - kB4; src = w4; dst = w4bf;
    }
    float4v v = ((const float4v*)src)[j];
    u16x4 o;
    o.x = f2bf(v.x); o.y = f2bf(v.y); o.z = f2bf(v.z); o.w = f2bf(v.w);
    ((u16x4*)dst)[j] = o;
}

// ---------------- GEMM: C[M,N] = A[M,K] * W[N,K]^T ----------------
// m97 staging + double-buffered LDS, one barrier per K-iter. Used for the
// small-N GEMMs (G1/G2/G4) where 256^2 tiles would under-occupy the grid.
// blockIdx.z = split-K slice (partials at Cout + z*M*N, fp32, no resid).
// NOTE (R7 lesson): keep grid >= 2 blocks/CU — at 1 block/CU the 2-barrier
// lockstep loses its co-resident-block latency hiding (SK=2 regressed 17µs).
// R9: bf16 output path (G1) now routes through an LDS transpose (staging
// LDS is dead post-loop) -> coalesced u16x8 stores instead of 64 scattered
// 2B stores/thread (same fix as G3's R3 epilogue). Shared memory unified
// as sm[4][4096] (same 32KB) so the 128x128 u16 tile fits contiguously.
template <bool OUT_BF16, bool GATED = false>
__global__ __launch_bounds__(256)
void gemm_bt(const u16* __restrict__ A, const u16* __restrict__ W,
             void* __restrict__ Cout, const float* __restrict__ resid,
             int M, int N, int K) {
    __shared__ u16 sm[4][4096];   // As = sm[0],sm[1]; Bs = sm[2],sm[3]
    const int tid = threadIdx.x;
    const int lane = tid & 63;
    const int w = __builtin_amdgcn_readfirstlane(tid >> 6);
    const int wm = w >> 1, wn = w & 1;
    const int bm = blockIdx.y * 128;
    const int bn = blockIdx.x * 128;
    const int z = blockIdx.z;
    const int Kchunk = K / gridDim.z;
    const int k0 = z * Kchunk;

    f32x4 acc[4][4];
#pragma unroll
    for (int i = 0; i < 4; i++)
#pragma unroll
        for (int j = 0; j < 4; j++) acc[i][j] = {0.f, 0.f, 0.f, 0.f};

    // staging: lane -> (row = lane>>2, kchunk = lane&3): global-coalesced
    const int srow = lane >> 2;          // 0..15
    const int scol = (lane & 3) * 8;     // k elem
    const u16* gA = A + (size_t)(bm + w * 32 + srow) * K + k0 + scol;
    const u16* gB = W + (size_t)(bn + w * 32 + srow) * K + k0 + scol;
    const size_t rstep = (size_t)16 * K;

    const int sbase0 = (w * 32) * 32;
    const int sbase1 = (w * 32 + 16) * 32;
    const int fra = (lane & 15) * 32 + (lane >> 4) * 8;

    // prologue: stage tile 0 into buffer 0
    gld16(gA, &sm[0][sbase0]);
    gld16(gA + rstep, &sm[0][sbase1]);
    gld16(gB, &sm[2][sbase0]);
    gld16(gB + rstep, &sm[2][sbase1]);

    const int nk = Kchunk >> 5;
    for (int i = 0; i < nk; i++) {
        const int cur = i & 1, nxt = cur ^ 1;
        __syncthreads();   // drains DMA for buf[cur]; buf[nxt] reads finished
        if (i + 1 < nk) {
            int kt2 = (i + 1) * 32;
            gld16(gA + kt2, &sm[nxt][sbase0]);
            gld16(gA + kt2 + rstep, &sm[nxt][sbase1]);
            gld16(gB + kt2, &sm[2 + nxt][sbase0]);
            gld16(gB + kt2 + rstep, &sm[2 + nxt][sbase1]);
        }
        bf16x8 av[4], bv[4];
#pragma unroll
        for (int mi = 0; mi < 4; mi++)
            av[mi] = *(const bf16x8*)&sm[cur][(wm * 64 + mi * 16) * 32 + fra];
#pragma unroll
        for (int ni = 0; ni < 4; ni++)
            bv[ni] = *(const bf16x8*)&sm[2 + cur][(wn * 64 + ni * 16) * 32 + fra];
#pragma unroll
        for (int mi = 0; mi < 4; mi++)
#pragma unroll
            for (int ni = 0; ni < 4; ni++)
                acc[mi][ni] = __builtin_amdgcn_mfma_f32_16x16x32_bf16(av[mi], bv[ni], acc[mi][ni], 0, 0, 0);
    }

    const int rb = bm + wm * 64 + ((lane >> 4) << 2);
    const int cb = bn + wn * 64 + (lane & 15);
    if (GATED) {
        u16* Cb = (u16*)Cout;
        const int NG = N >> 1;
        const int gc0 = ((bn + wn * 64) >> 1) + (lane & 15);
#pragma unroll
        for (int mi = 0; mi < 4; mi++) {
#pragma unroll
            for (int p = 0; p < 2; p++) {
#pragma unroll
                for (int r = 0; r < 4; r++) {
                    float a = acc[mi][2 * p][r];
                    float g = acc[mi][2 * p + 1][r];
                    Cb[(size_t)(rb + mi * 16 + r) * NG + gc0 + p * 16] =
                        f2bf(a * silu_(g));
                }
            }
        }
        return;
    }
    if (OUT_BF16) {
        // LDS transpose epilogue (resid unused on this path — G1 passes null).
        // Write swizzle col ^= ((row>>2)&7)<<4: the 4 slots of one b16-store
        // land on 4 disjoint 8-bank groups (1 word/bank); reads cover full
        // 256B rows -> conflict-free.
        __syncthreads();                   // all waves past final ds_reads
        u16* cst = &sm[0][0];              // 16384 u16 = 32KB = 128x128 tile
        const int slot = lane >> 4, r0a = lane & 15;
#pragma unroll
        for (int mi = 0; mi < 4; mi++) {
#pragma unroll
            for (int ni = 0; ni < 4; ni++) {
#pragma unroll
                for (int r = 0; r < 4; r++) {
                    int row = wm * 64 + mi * 16 + slot * 4 + r;
                    int col = wn * 64 + ni * 16 + r0a;
                    int colp = col ^ (((row >> 2) & 7) << 4);
                    cst[row * 128 + colp] = f2bf(acc[mi][ni][r]);
                }
            }
        }
        __syncthreads();
        u16* Cb = (u16*)Cout;
#pragma unroll
        for (int k2 = 0; k2 < 8; k2++) {
            int ch = k2 * 256 + tid;       // 2048 chunks of 8 u16 (16B)
            int row = ch >> 4, c8 = ch & 15;
            int addr = row * 128 +
                       ((((c8 >> 1) ^ ((row >> 2) & 7)) << 4) | ((c8 & 1) << 3));
            *(u16x8*)(Cb + (size_t)(bm + row) * N + bn + c8 * 8) =
                *(const u16x8*)&cst[addr];
        }
        return;
    }
    float* Cf = (float*)Cout + (size_t)z * M * N;
#pragma unroll
    for (int mi = 0; mi < 4; mi++) {
#pragma unroll
        for (int ni = 0; ni < 4; ni++) {
#pragma unroll
            for (int r = 0; r < 4; r++) {
                size_t offo = (size_t)(rb + mi * 16 + r) * N + (cb + ni * 16);
                float v = acc[mi][ni][r];
                if (resid) v += resid[offo];
                Cf[offo] = v;
            }
        }
    }
}

// ---------------- 256x256 8-phase GEMM (gated, for G3) — v4 ----------------
// Best measured form (42.8-43.3 µs): 8 waves 2Mx4N, one counted vmcnt per
// tile, LDS-transposed coalesced epilogue, XCD rectangle map.
#define VMCNT6 asm volatile("s_waitcnt vmcnt(6)" ::: "memory")
#define VMCNT0 asm volatile("s_waitcnt vmcnt(0)" ::: "memory")

__global__ __launch_bounds__(512, 2)
void gemm256_gated(const u16* __restrict__ A, const u16* __restrict__ W,
                   u16* __restrict__ Cout, int M, int N, int K) {
    __shared__ u16 lds[2][2][2][2][4096];   // [dbuf][mat][half][kh][128*32]
    const int tid = threadIdx.x;
    const int lane = tid & 63;
    const int w = __builtin_amdgcn_readfirstlane(tid >> 6);
    const int wm = w >> 2;                  // 0..1  (M)
    const int wn = w & 3;                   // 0..3  (N)
    const int wnh = wn >> 1, wnl = wn & 1;

    // XCD-aware rectangle map (grid 8 M-tiles x 32 N-tiles = 256 blocks):
    const int lin = blockIdx.x;
    const int xcd = lin & 7, j = lin >> 3;
    const int bm = (((xcd >> 2) << 2) + (j & 3)) << 8;
    const int bn = (((xcd & 3) << 3) + (j >> 2)) << 8;

    // staging source addresses (pre-swizzled global k-slot; v2(r) XOR keeps
    // a 16-row fragment group spread 2-lanes-per-bank-quad on ds_read_b128)
    const int rst = tid >> 2, sst = tid & 3;
    const int vst = (((rst >> 1) & 1) << 1) | ((rst >> 2) & 1);
    const u16* gA0 = A + (size_t)(bm + rst) * K + ((sst ^ vst) << 3);
    const u16* gB0 = W + (size_t)(bn + rst) * K + ((sst ^ vst) << 3);
    const size_t hstep = (size_t)128 * K;
    const int wq512 = w * 512;              // wave's 1KB-block offset (elems)

    // fragment read offset (swizzled)
    const int r0a = lane & 15, slot = lane >> 4;
    const int v2a = (((r0a >> 1) & 1) << 1) | ((r0a >> 2) & 1);
    const int fro = r0a * 32 + ((slot ^ v2a) << 3);

    f32x4 acc[8][4];
#pragma unroll
    for (int i = 0; i < 8; i++)
#pragma unroll
        for (int j_ = 0; j_ < 4; j_++) acc[i][j_] = {0.f, 0.f, 0.f, 0.f};
    bf16x8 bv[4];
    const int nt = K >> 6;                  // K-tiles of 64 (>= 4 assumed)

#define STAGE(d, mat, kh, kt)                                               \
    { const u16* g_ = ((mat) ? gB0 : gA0) + (size_t)(kt) * 64 + (kh) * 32;  \
      gld16(g_, &lds[d][mat][0][kh][wq512]);                                \
      gld16(g_ + hstep, &lds[d][mat][1][kh][wq512]); }

#define LDA_FRAG(dst, d, kh, mfb)                                           \
    _Pragma("unroll") for (int i_ = 0; i_ < 4; i_++)                        \
        dst[i_] = *(const bf16x8*)&lds[d][0][wm][kh][((mfb) + i_) * 512 + fro];

#define LDB_FRAG(d, kh)                                                     \
    _Pragma("unroll") for (int i_ = 0; i_ < 4; i_++)                        \
        bv[i_] = *(const bf16x8*)&lds[d][1][wnh][kh][wnl * 2048 + i_ * 512 + fro];

#define PHASE_TAIL(g4, ...)                                                 \
    __builtin_amdgcn_s_barrier();                                           \
    asm volatile("s_waitcnt lgkmcnt(0)" ::: "memory");                      \
    __builtin_amdgcn_s_setprio(1);                                          \
    _Pragma("unroll") for (int i_ = 0; i_ < 4; i_++)                        \
        _Pragma("unroll") for (int n_ = 0; n_ < 4; n_++)                    \
            acc[(g4) * 4 + i_][n_] = __builtin_amdgcn_mfma_f32_16x16x32_bf16( \
                av[i_], bv[n_], acc[(g4) * 4 + i_][n_], 0, 0, 0);           \
    __builtin_amdgcn_s_setprio(0);                                          \
    __VA_ARGS__;                                                            \
    __builtin_amdgcn_s_barrier();

#define TILE(T, D)                                                          \
    { /* ph0: MFMA(k0, mf0-3) */                                            \
      { bf16x8 av[4]; LDB_FRAG(D, 0); LDA_FRAG(av, D, 0, 0);                \
        if ((T) + 1 < nt) STAGE(D ^ 1, 0, 1, (T) + 1);                      \
        PHASE_TAIL(0, ((void)0)) }                                          \
      /* ph1: MFMA(k0, mf4-7) */                                            \
      { bf16x8 av[4]; LDA_FRAG(av, D, 0, 4);                                \
        if ((T) + 2 < nt) STAGE(D, 1, 0, (T) + 2);                          \
        PHASE_TAIL(1, ((void)0)) }                                          \
      /* ph2: MFMA(k1, mf0-3) */                                            \
      { bf16x8 av[4]; LDB_FRAG(D, 1); LDA_FRAG(av, D, 1, 0);                \
        if ((T) + 2 < nt) STAGE(D, 0, 0, (T) + 2);                          \
        PHASE_TAIL(0, ((void)0)) }                                          \
      /* ph3: MFMA(k1, mf4-7) + the tile's single counted vmcnt */          \
      { bf16x8 av[4]; LDA_FRAG(av, D, 1, 4);                                \
        if ((T) + 2 < nt) STAGE(D, 1, 1, (T) + 2);                          \
        PHASE_TAIL(1, if ((T) + 2 < nt) { VMCNT6; }                         \
                      else if ((T) + 1 < nt) { VMCNT0; }) }                 \
    }

    // prologue: tile0 all 4 units + tile1 first 3 units (steady-state order;
    // A-k1(t1) is staged by TILE(0).ph0). vmcnt(6) waits loads 0-7 = all of
    // tile0; the 6 newest (tile1 units) stay in flight.
    STAGE(0, 1, 0, 0);   // B-k0 (t0)
    STAGE(0, 0, 0, 0);   // A-k0 (t0)
    STAGE(0, 1, 1, 0);   // B-k1 (t0)
    STAGE(0, 0, 1, 0);   // A-k1 (t0)
    STAGE(1, 1, 0, 1);   // B-k0 (t1)
    STAGE(1, 0, 0, 1);   // A-k0 (t1)
    STAGE(1, 1, 1, 1);   // B-k1 (t1)
    VMCNT6;
    __builtin_amdgcn_s_barrier();

    for (int tt = 0; tt < nt; tt += 2) {
        TILE(tt, 0)
        TILE(tt + 1, 1)
    }

#undef TILE
#undef PHASE_TAIL
#undef LDB_FRAG
#undef LDA_FRAG
#undef STAGE

    // gated epilogue: a*silu(g) -> LDS (padded rows) -> coalesced stores.
    // fc1 row-permutation puts (a,g) in nf pair (2p, 2p+1) of the same lane;
    // local gate-col = wn*32 + p*16 + (lane&15); local row = wm*128+mf*16+slot*4+r.
    __syncthreads();                       // staging LDS dead; safe to reuse
    u16* cst = (u16*)&lds[0][0][0][0][0];
    constexpr int LDE = 136;               // 272B rows: 16B-aligned, bank-spread
#pragma unroll
    for (int mf = 0; mf < 8; mf++) {
#pragma unroll
        for (int p = 0; p < 2; p++) {
#pragma unroll
            for (int r = 0; r < 4; r++) {
                float a = acc[mf][2 * p][r];
                float g = acc[mf][2 * p + 1][r];
                cst[(wm * 128 + mf * 16 + slot * 4 + r) * LDE +
                    wn * 32 + p * 16 + r0a] = f2bf(a * silu_(g));
            }
        }
    }
    __syncthreads();
    const int NG = N >> 1;
#pragma unroll
    for (int k = 0; k < 8; k++) {
        int ch = k * 512 + tid;            // 4096 chunks of 8 u16 (16B)
        int row = ch >> 4, c8 = (ch & 15) * 8;
        *(u16x8*)(Cout + (size_t)(bm + row) * NG + (bn >> 1) + c8) =
            *(const u16x8*)&cst[row * LDE + c8];
    }
}

// ---------------- split-K reduce (SK=4) + residual, fp32 out ----------------
__global__ __launch_bounds__(256)
void splitk_reduce_kernel(const float* __restrict__ Cp, const float* __restrict__ resid,
                          float* __restrict__ out, int mn4) {
    int i = blockIdx.x * 256 + threadIdx.x;
    if (i >= mn4) return;
    constexpr size_t MN = (size_t)kRows * kD;
    float4v s0 = ((const float4v*)Cp)[i];
    float4v s1 = ((const float4v*)(Cp + MN))[i];
    float4v s2 = ((const float4v*)(Cp + 2 * MN))[i];
    float4v s3 = ((const float4v*)(Cp + 3 * MN))[i];
    float4v r = ((const float4v*)resid)[i];
    float4v o;
    o.x = s0.x + s1.x + s2.x + s3.x + r.x;
    o.y = s0.y + s1.y + s2.y + s3.y + r.y;
    o.z = s0.z + s1.z + s2.z + s3.z + r.z;
    o.w = s0.w + s1.w + s2.w + s3.w + r.w;
    ((float4v*)out)[i] = o;
}

// ------- fused: split-K(4) reduce + residual + RMSNorm(1024) -> x2, xn bf16
__global__ __launch_bounds__(256)
void reduce_rms_kernel(const float* __restrict__ Cp, const float* __restrict__ resid,
                       float* __restrict__ x2, const float* __restrict__ rmsw,
                       u16* __restrict__ xnbf) {
    const int row = blockIdx.x;
    const int tid = threadIdx.x;
    constexpr size_t MN = (size_t)kRows * kD;
    size_t i = (size_t)row * (kD / 4) + tid;
    float4v s0 = ((const float4v*)Cp)[i];
    float4v s1 = ((const float4v*)(Cp + MN))[i];
    float4v s2 = ((const float4v*)(Cp + 2 * MN))[i];
    float4v s3 = ((const float4v*)(Cp + 3 * MN))[i];
    float4v r = ((const float4v*)resid)[i];
    float4v v;
    v.x = s0.x + s1.x + s2.x + s3.x + r.x;
    v.y = s0.y + s1.y + s2.y + s3.y + r.y;
    v.z = s0.z + s1.z + s2.z + s3.z + r.z;
    v.w = s0.w + s1.w + s2.w + s3.w + r.w;
    ((float4v*)x2)[i] = v;
    float ss = v.x * v.x + v.y * v.y + v.z * v.z + v.w * v.w;
#pragma unroll
    for (int off = 32; off > 0; off >>= 1) ss += __shfl_down(ss, off);
    __shared__ float red[4];
    int wv = tid >> 6, lane = tid & 63;
    if (lane == 0) red[wv] = ss;
    __syncthreads();
    ss = red[0] + red[1] + red[2] + red[3];
    float rstd = rsqrtf(ss * (1.f / kD) + 1e-5f);
    float4v wv4 = ((const float4v*)rmsw)[tid];
    u16x4 o;
    o.x = f2bf(v.x * rstd * wv4.x);
    o.y = f2bf(v.y * rstd * wv4.y);
    o.z = f2bf(v.z * rstd * wv4.z);
    o.w = f2bf(v.w * rstd * wv4.w);
    ((u16x4*)xnbf)[i] = o;
}

// ---------------- fused depthwise causal conv + silu + dt ----------------
__global__ __launch_bounds__(256)
void convdt_kernel(const u16* __restrict__ zxbf, const float* __restrict__ convw,
                   const float* __restrict__ convb, u16* __restrict__ xsbf,
                   float* __restrict__ BCf, const float* __restrict__ dt_bias,
                   float* __restrict__ dtf) {
    int c = blockIdx.x * 256 + threadIdx.x;
    int row = blockIdx.y;                 // b*1024 + s
    if (c >= kConvDim + kHeads) return;
    if (c < kConvDim) {
        int s = row & (kS - 1);
        float acc = convb[c];
#pragma unroll
        for (int j = 0; j < 4; j++) {
            int sj = s - 3 + j;
            if (sj >= 0)
                acc += bf2f(zxbf[(size_t)(row - 3 + j) * kDprojPad + kDinner + c]) * convw[c * 4 + j];
        }
        float v = silu_(acc);
        if (c < kDinner) xsbf[(size_t)row * kDinner + c] = f2bf(v);
        else BCf[(size_t)row * 128 + (c - kDinner)] = v;
    } else {
        int h = c - kConvDim;
        float raw = bf2f(zxbf[(size_t)row * kDprojPad + (kDinner + kConvDim) + h]) + dt_bias[h];
        float dt = (raw > 20.f) ? raw : log1pf(__expf(raw));
        dtf[(size_t)row * kHeads + h] = dt;
    }
}

// ---------------- Phase A: intra-chunk scan as chunked matmul (MFMA) --------
// Mamba-2 chunk form, per (b,h,chunk):
//   la[t]  = -A_h * cumsum(dt)        (log of cumulative decay a[t])
//   G      = C @ B^T                  (64x64, K=n=64)
//   M[t,s] = G[t,s]*dt_s*exp(la_t-la_s), masked s<=t
//   Y      = M @ X  (+ D*x)          (64x64, K=s=64)
//   S[p,n] = sum_s x[s,p]*dt_s*exp(la63-la_s)*B[s,n]   (chunk-end state)
// Precision: hi/lo compensated bf16 splits keep all products fp32-accurate.
__global__ __launch_bounds__(256)
void scan_chunk_kernel(const u16* __restrict__ xsbf, const float* __restrict__ BCf,
                       const float* __restrict__ dtf, const float* __restrict__ A_log,
                       const float* __restrict__ Dv, u16* __restrict__ ysbf,
                       float* __restrict__ Pf, float* __restrict__ Scf) {
    constexpr int LDT = 72;   // row stride (elems); 144B rows -> conflict-free b128
    __shared__ __align__(16) char smem[65280];
    u16* Chi  = (u16*)(smem);
    u16* Clo  = (u16*)(smem + 9216);
    u16* Bhi  = (u16*)(smem + 18432);
    u16* Blo  = (u16*)(smem + 27648);
    u16* BThi = (u16*)(smem + 36864);
    u16* BTlo = (u16*)(smem + 46080);
    u16* xT   = (u16*)(smem + 55296);
    float* laS  = (float*)(smem + 64512);
    float* dtS  = (float*)(smem + 64768);
    float* wscS = (float*)(smem + 65024);
    // overlays (all transitions barrier-separated):
    u16* Mhi  = Clo;   // Clo dead after G
    u16* Mlo  = Bhi;   // Bhi dead after G + transpose
    u16* ybuf = Chi;   // Chi dead after G

    const int c = blockIdx.x, h = blockIdx.y, b = blockIdx.z;
    const int tid = threadIdx.x;
    const int lane = tid & 63;
    const int w = __builtin_amdgcn_readfirstlane(tid >> 6);
    const int row0 = b * kS + c * kL;
    const int frow = lane & 15;
    const int fk = (lane >> 4) * 8;
    const int q4 = (lane >> 4) * 4;
    const int w16 = w * 16;

    // ---- stage B/C (hi/lo split) ----
#pragma unroll
    for (int k = 0; k < 8; k++) {
        int e4 = k * 256 + tid;              // 2048 float4s = 64 rows x 128
        int t = e4 >> 5, col = (e4 & 31) * 4;
        float4v v = *(const float4v*)(BCf + (size_t)(row0 + t) * 128 + col);
        u16x4 hi, lo;
        hi.x = f2bf(v.x); lo.x = f2bf(v.x - bf2f(hi.x));
        hi.y = f2bf(v.y); lo.y = f2bf(v.y - bf2f(hi.y));
        hi.z = f2bf(v.z); lo.z = f2bf(v.z - bf2f(hi.z));
        hi.w = f2bf(v.w); lo.w = f2bf(v.w - bf2f(hi.w));
        int cc = col & 63;
        u16* dh = (col < 64) ? Bhi : Chi;
        u16* dl = (col < 64) ? Blo : Clo;
        *(u16x4*)&dh[t * LDT + cc] = hi;
        *(u16x4*)&dl[t * LDT + cc] = lo;
    }
    // ---- stage x transposed: xT[p][t] ----
#pragma unroll
    for (int k = 0; k < 2; k++) {
        int e8 = k * 256 + tid;
        int t = e8 >> 3, p8 = (e8 & 7) * 8;
        u16x8 xv = *(const u16x8*)(xsbf + (size_t)(row0 + t) * kDinner + h * 64 + p8);
#pragma unroll
        for (int j = 0; j < 8; j++) xT[(p8 + j) * LDT + t] = xv[j];
    }
    // ---- dt load + log-decay prefix scan (wave 0) ----
    if (tid < 64) {
        float d = dtf[(size_t)(row0 + tid) * kHeads + h];
        dtS[tid] = d;
        float cs = d;
#pragma unroll
        for (int off = 1; off < 64; off <<= 1) {
            float o = __shfl_up(cs, off);
            if (lane >= off) cs += o;
        }
        float A_h = __expf(A_log[h]);
        float la = -A_h * cs;
        laS[tid] = la;
        Pf[(size_t)(row0 + tid) * kHeads + h] = __expf(la);
        float la63 = __shfl(la, 63);
        wscS[tid] = d * __expf(la63 - la);
    }
    __syncthreads();

    // ---- G = C @ B^T (only lower-triangular tile columns nt <= w) ----
    f32x4 accG[4];
#pragma unroll
    for (int i = 0; i < 4; i++) accG[i] = {0.f, 0.f, 0.f, 0.f};
#pragma unroll
    for (int kb = 0; kb < 2; kb++) {
        bf16x8 ch = *(const bf16x8*)&Chi[(w16 + frow) * LDT + kb * 32 + fk];
        bf16x8 cl = *(const bf16x8*)&Clo[(w16 + frow) * LDT + kb * 32 + fk];
#pragma unroll
        for (int nt = 0; nt < 4; nt++) {
            if (nt <= w) {
                bf16x8 bh = *(const bf16x8*)&Bhi[(nt * 16 + frow) * LDT + kb * 32 + fk];
                bf16x8 bl = *(const bf16x8*)&Blo[(nt * 16 + frow) * LDT + kb * 32 + fk];
                accG[nt] = __builtin_amdgcn_mfma_f32_16x16x32_bf16(ch, bh, accG[nt], 0, 0, 0);
                accG[nt] = __builtin_amdgcn_mfma_f32_16x16x32_bf16(ch, bl, accG[nt], 0, 0, 0);
                accG[nt] = __builtin_amdgcn_mfma_f32_16x16x32_bf16(cl, bh, accG[nt], 0, 0, 0);
            }
        }
    }
    // ---- BT transpose (for S's B-operand) ----
#pragma unroll
    for (int k = 0; k < 16; k++) {
        int e = k * 256 + tid;
        int s = e >> 6, n = e & 63;
        BThi[n * LDT + s] = Bhi[s * LDT + n];
        BTlo[n * LDT + s] = Blo[s * LDT + n];
    }
    __syncthreads();   // G reads of Clo/Bhi/Chi done -> M/ybuf overlays legal

    // ---- M build: scale G by dt_s * exp(la_t - la_s), mask, hi/lo split ----
    f32x4 la4 = *(const f32x4*)&laS[w16 + q4];
#pragma unroll
    for (int nt = 0; nt < 4; nt++) {
        int s = nt * 16 + frow;
        float las = laS[s], dts = dtS[s];
#pragma unroll
        for (int r = 0; r < 4; r++) {
            int t = w16 + q4 + r;
            float f = 0.f;
            if (nt <= w && s <= t)
                f = dts * __expf(la4[r] - las) * accG[nt][r];
            u16 mh = f2bf(f);
            u16 ml = f2bf(f - bf2f(mh));
            Mhi[t * LDT + s] = mh;
            Mlo[t * LDT + s] = ml;
        }
    }

    // ---- Y = M @ X  (per-wave own rows; same-wave LDS RAW is in-order) ----
    f32x4 accY[4];
#pragma unroll
    for (int i = 0; i < 4; i++) accY[i] = {0.f, 0.f, 0.f, 0.f};
#pragma unroll
    for (int kb = 0; kb < 2; kb++) {
        bf16x8 mh = *(const bf16x8*)&Mhi[(w16 + frow) * LDT + kb * 32 + fk];
        bf16x8 ml = *(const bf16x8*)&Mlo[(w16 + frow) * LDT + kb * 32 + fk];
#pragma unroll
        for (int nt = 0; nt < 4; nt++) {
            bf16x8 xv = *(const bf16x8*)&xT[(nt * 16 + frow) * LDT + kb * 32 + fk];
            accY[nt] = __builtin_amdgcn_mfma_f32_16x16x32_bf16(mh, xv, accY[nt], 0, 0, 0);
            accY[nt] = __builtin_amdgcn_mfma_f32_16x16x32_bf16(ml, xv, accY[nt], 0, 0, 0);
        }
    }

    // ---- S = Xw^T @ B  (Xw = x * dt * exp(la63-la), hi/lo in regs) ----
    f32x4 accS[4];
#pragma unroll
    for (int i = 0; i < 4; i++) accS[i] = {0.f, 0.f, 0.f, 0.f};
#pragma unroll
    for (int kb = 0; kb < 2; kb++) {
        u16x8 xu = __builtin_bit_cast(u16x8, *(const bf16x8*)&xT[(w16 + frow) * LDT + kb * 32 + fk]);
        f32x4 w0v = *(const f32x4*)&wscS[kb * 32 + fk];
        f32x4 w1v = *(const f32x4*)&wscS[kb * 32 + fk + 4];
        u16x8 xh, xl;
#pragma unroll
        for (int j = 0; j < 8; j++) {
            float wv = (j < 4) ? w0v[j] : w1v[j - 4];
            float f = bf2f(xu[j]) * wv;
            u16 hh = f2bf(f);
            xh[j] = hh;
            xl[j] = f2bf(f - bf2f(hh));
        }
        bf16x8 xwh = __builtin_bit_cast(bf16x8, xh);
        bf16x8 xwl = __builtin_bit_cast(bf16x8, xl);
#pragma unroll
        for (int nt = 0; nt < 4; nt++) {
            bf16x8 bh = *(const bf16x8*)&BThi[(nt * 16 + frow) * LDT + kb * 32 + fk];
            bf16x8 bl = *(const bf16x8*)&BTlo[(nt * 16 + frow) * LDT + kb * 32 + fk];
            accS[nt] = __builtin_amdgcn_mfma_f32_16x16x32_bf16(xwh, bh, accS[nt], 0, 0, 0);
            accS[nt] = __builtin_amdgcn_mfma_f32_16x16x32_bf16(xwh, bl, accS[nt], 0, 0, 0);
            accS[nt] = __builtin_amdgcn_mfma_f32_16x16x32_bf16(xwl, bh, accS[nt], 0, 0, 0);
        }
    }

    // ---- epilogue: Y += D*x -> ybuf; S -> Scf ----
    const float Dh = Dv[h];
    const int bhc = (b * 32 + h) * kNC + c;
    float* Sb = Scf + (size_t)bhc * 4096;
#pragma unroll
    for (int nt = 0; nt < 4; nt++) {
#pragma unroll
        for (int r = 0; r < 4; r++) {
            int t = w16 + q4 + r;
            int pc = nt * 16 + frow;
            float y = accY[nt][r] + Dh * bf2f(xT[pc * LDT + t]);
            ybuf[t * 64 + pc] = f2bf(y);
            Sb[t * 64 + pc] = accS[nt][r];   // t here = p-row (same index math)
        }
    }
    __syncthreads();
#pragma unroll
    for (int k = 0; k < 2; k++) {
        int e8 = k * 256 + tid;
        int t = e8 >> 3, col8 = (e8 & 7) * 8;
        *(u16x8*)(ysbf + (size_t)(row0 + t) * kDinner + h * 64 + col8) =
            *(u16x8*)&ybuf[t * 64 + col8];
    }
}

// ---------------- Phase B: sequential chunk-state combine ----------------
// 1024 blocks: recurrence serial only in c; 4096 state columns independent.
__global__ __launch_bounds__(256)
void chunk_state_kernel(const float* __restrict__ Scf, const float* __restrict__ Pf,
                        float* __restrict__ Hinf) {
    const int bh = blockIdx.x;            // 64 = (b,h)
    const int b = bh >> 5, h = bh & 31;
    const int eo = blockIdx.y * 256 + threadIdx.x;   // state elem 0..4095
    float hreg = 0.f;
    for (int c = 0; c < kNC - 1; c++) {
        float Q = Pf[(size_t)(b * kS + c * kL + kL - 1) * kHeads + h];
        hreg = Q * hreg + Scf[(size_t)(bh * kNC + c) * 4096 + eo];
        Hinf[(size_t)(bh * kNC + c + 1) * 4096 + eo] = hreg;
    }
}

// ---------------- Phase C: cross-chunk correction ----------------
__global__ __launch_bounds__(256)
void chunk_corr_kernel(const float* __restrict__ Hinf, const float* __restrict__ BCf,
                       const float* __restrict__ Pf, u16* __restrict__ ysbf) {
    const int c = blockIdx.x + 1;
    const int h = blockIdx.y, b = blockIdx.z;
    const int tid = threadIdx.x;
    const int lane = tid & 63, wq = tid >> 6;
    __shared__ float Hin_lds[64 * 65];
    __shared__ float C_lds[kL * 64];
    const int bh = b * 32 + h;
    const size_t hbase = (size_t)(bh * kNC + c) * 4096;
#pragma unroll
    for (int k = 0; k < 16; k++) {
        int e = k * 256 + tid;
        Hin_lds[(e >> 6) * 65 + (e & 63)] = Hinf[hbase + e];
    }
    const int row0 = b * kS + c * kL;
#pragma unroll
    for (int k = 0; k < 4; k++) {
        int e4 = k * 256 + tid;
        int t = e4 >> 4, n4 = (e4 & 15) * 4;
        *(float4v*)&C_lds[t * 64 + n4] =
            *(const float4v*)(BCf + (size_t)(row0 + t) * 128 + 64 + n4);
    }
    __syncthreads();

    float hr[64];
#pragma unroll
    for (int n = 0; n < 64; n++) hr[n] = Hin_lds[lane * 65 + n];

    for (int tt = 0; tt < 16; tt++) {
        int t = wq * 16 + tt;
        float corr = 0.f;
#pragma unroll
        for (int n4 = 0; n4 < 16; n4++) {
            float4v cv = *(const float4v*)&C_lds[t * 64 + n4 * 4];
            corr += cv.x * hr[n4 * 4] + cv.y * hr[n4 * 4 + 1] +
                    cv.z * hr[n4 * 4 + 2] + cv.w * hr[n4 * 4 + 3];
        }
        float Pt = Pf[(size_t)(row0 + t) * kHeads + h];
        size_t yoff = (size_t)(row0 + t) * kDinner + h * 64 + lane;
        ysbf[yoff] = f2bf(bf2f(ysbf[yoff]) + Pt * corr);
    }
}

// ---------------- gate (silu(z)) + rmsnorm over 2048 ----------------
__global__ __launch_bounds__(256)
void gatenorm_kernel(const u16* __restrict__ ysbf, const u16* __restrict__ zxbf,
                     const float* __restrict__ normw, u16* __restrict__ ybf) {
    const int row = blockIdx.x;
    const int tid = threadIdx.x;
    float v[8];
    float ss = 0.f;
#pragma unroll
    for (int i = 0; i < 8; i++) {
        int idx = i * 256 + tid;
        float y = bf2f(ysbf[(size_t)row * kDinner + idx]);
        float z = bf2f(zxbf[(size_t)row * kDprojPad + idx]);
        v[i] = y * silu_(z);
        ss += v[i] * v[i];
    }
#pragma unroll
    for (int off = 32; off > 0; off >>= 1) ss += __shfl_down(ss, off);
    __shared__ float red[4];
    int wv = tid >> 6, lane = tid & 63;
    if (lane == 0) red[wv] = ss;
    __syncthreads();
    ss = red[0] + red[1] + red[2] + red[3];
    float rstd = rsqrtf(ss * (1.f / kDinner) + 1e-5f);
#pragma unroll
    for (int i = 0; i < 8; i++) {
        int idx = i * 256 + tid;
        ybf[(size_t)row * kDinner + idx] = f2bf(v[i] * rstd * normw[idx]);
    }
}

extern "C" void kernel_launch(void* const* d_in, const int* in_sizes, int n_in,
                              void* d_out, int out_size, void* d_ws, size_t ws_size,
                              hipStream_t stream) {
    const float* x         = (const float*)d_in[0];
    const float* in_proj_w = (const float*)d_in[1];
    const float* conv_w    = (const float*)d_in[2];
    const float* conv_b    = (const float*)d_in[3];
    const float* dt_bias   = (const float*)d_in[4];
    const float* A_log     = (const float*)d_in[5];
    const float* Dvec      = (const float*)d_in[6];
    const float* ssm_norm_w= (const float*)d_in[7];
    const float* out_proj_w= (const float*)d_in[8];
    const float* rms_w     = (const float*)d_in[9];
    const float* fc1_w     = (const float*)d_in[10];
    const float* fc2_w     = (const float*)d_in[11];
    float* out = (float*)d_out;

    char* ws = (char*)d_ws;
    size_t off = 0;
    auto alloc = [&](size_t bytes) -> void* {
        void* p = ws + off;
        off += (bytes + 255) & ~(size_t)255;
        return p;
    };
    u16*   xbf  = (u16*)alloc((size_t)kRows * kD * 2);
    u16*   w1bf = (u16*)alloc((size_t)kDprojPad * kD * 2);
    u16*   w2bf = (u16*)alloc((size_t)kD * kDinner * 2);
    u16*   w3bf = (u16*)alloc((size_t)kHmlp * kD * 2);
    u16*   w4bf = (u16*)alloc((size_t)kD * kHhalf * 2);
    u16*   zxbf = (u16*)alloc((size_t)kRows * kDprojPad * 2);
    u16*   xsbf = (u16*)alloc((size_t)kRows * kDinner * 2);
    float* BCf  = (float*)alloc((size_t)kRows * 128 * 4);
    float* dtf  = (float*)alloc((size_t)kRows * kHeads * 4);
    float* Pf   = (float*)alloc((size_t)kRows * kHeads * 4);
    u16*   ysbf = (u16*)alloc((size_t)kRows * kDinner * 2);
    u16*   ybf  = (u16*)alloc((size_t)kRows * kDinner * 2);
    float* x2   = (float*)alloc((size_t)kRows * kD * 4);
    u16*   xnbf = (u16*)alloc((size_t)kRows * kD * 2);
    u16*   h1bf = (u16*)alloc((size_t)kRows * kHmlp * 2);   // scratch region
    u16*   gbf  = (u16*)alloc((size_t)kRows * kHhalf * 2);
    // Aliased scratch (h1bf region is scratch-only now):
    //   Scf/Hinf (16MB each) during scan; Cp (4*2048*1024 f32 = 33.55MB)
    //   during G2 split-K and G4 split-K.
    float* Scf  = (float*)gbf;
    float* Hinf = (float*)h1bf;
    float* Cp   = (float*)h1bf;
    (void)ws_size; (void)in_sizes; (void)n_in; (void)out_size;

    // all casts in one dispatch (fc1 row-permuted for the gated epilogue)
    cast_all_kernel<<<kB5 / 256, 256, 0, stream>>>(
        x, in_proj_w, out_proj_w, fc1_w, fc2_w, xbf, w1bf, w2bf, w3bf, w4bf);

    // G1: zxbcdt = x @ in_proj^T   (2048 x 4352, bf16 out, coalesced epilogue)
    gemm_bt<true><<<dim3(kDprojPad / 128, kRows / 128, 1), 256, 0, stream>>>(
        xbf, w1bf, zxbf, nullptr, kRows, kDprojPad, kD);

    // fused conv + dt
    convdt_kernel<<<dim3((kConvDim + kHeads + 255) / 256, kRows), 256, 0, stream>>>(
        zxbf, conv_w, conv_b, xsbf, BCf, dt_bias, dtf);

    // chunked scan (Phase A MFMA chunked-matmul form)
    scan_chunk_kernel<<<dim3(kNC, kHeads, 2), 256, 0, stream>>>(
        xsbf, BCf, dtf, A_log, Dvec, ysbf, Pf, Scf);
    chunk_state_kernel<<<dim3(64, 16), 256, 0, stream>>>(Scf, Pf, Hinf);
    chunk_corr_kernel<<<dim3(kNC - 1, kHeads, 2), 256, 0, stream>>>(Hinf, BCf, Pf, ysbf);

    gatenorm_kernel<<<kRows, 256, 0, stream>>>(ysbf, zxbf, ssm_norm_w, ybf);

    // G2: x2 = y @ out_proj^T + x   (split-K=4 -> 512 blocks = 2/CU, proven)
    gemm_bt<false><<<dim3(kD / 128, kRows / 128, 4), 256, 0, stream>>>(
        ybf, w2bf, Cp, nullptr, kRows, kD, kDinner);
    reduce_rms_kernel<<<kRows, 256, 0, stream>>>(Cp, x, x2, rms_w, xnbf);

    // G3+gate fused (256^2 8-phase v4): g = a*silu(g') from permuted fc1
    gemm256_gated<<<dim3((kRows >> 8) * (kHmlp >> 8)), 512, 0, stream>>>(
        xnbf, w3bf, gbf, kRows, kHmlp, kD);

    // G4: out = g @ fc2^T + x2   (split-K=4 -> 512 blocks = 2/CU, proven)
    gemm_bt<false><<<dim3(kD / 128, kRows / 128, 4), 256, 0, stream>>>(
        gbf, w4bf, Cp, nullptr, kRows, kD, kHhalf);
    splitk_reduce_kernel<<<(kRows * kD / 4 + 255) / 256, 256, 0, stream>>>(
        Cp, x2, out, kRows * kD / 4);
}